// Round 7
// baseline (1696.800 us; speedup 1.0000x reference)
//
#include <hip/hip_runtime.h>
#include <hip/hip_bf16.h>
#include <math.h>

// Model dims
#define DV   32000
#define DM   1024
#define DMLP 4096
#define DH   64
#define NH   16
#define NL   4
#define BATCH 2
#define S    2048
#define MTOK (BATCH*S)   // 4096 tokens

typedef __bf16 bf16_t;
typedef bf16_t bf16x8 __attribute__((ext_vector_type(8)));
typedef float  f32x4  __attribute__((ext_vector_type(4)));

#define AS1 __attribute__((address_space(1)))
#define AS3 __attribute__((address_space(3)))

__device__ __forceinline__ void gload16(const bf16_t* g, bf16_t* l) {
    __builtin_amdgcn_global_load_lds((const AS1 void*)g, (AS3 void*)l, 16, 0, 0);
}

__device__ __forceinline__ unsigned short bfbits(float v) {
    union { bf16_t b; unsigned short u; } c; c.b = (bf16_t)v; return c.u;
}
__device__ __forceinline__ float b2f(unsigned short u) {
    union { float f; unsigned v; } c; c.v = ((unsigned)u) << 16; return c.f;
}

// ---------------------------------------------------------------------------
// 256x256 deep-pipelined TN GEMM: C[M,N] = A[M,K] * B[N,K]^T.
// 512 threads = 8 waves (2M x 4N); per-wave output 128x64 (acc[8][4]).
// LDS 128 KiB: [2 buf][A,B][2 half][128x64 bf16], chunk-XOR swizzled.
// Counted vmcnt(2) (never 0 in-loop), 4 phases/K-tile each = 1 half-tile
// prefetch + 16-MFMA setprio cluster.
// MODE 0: bf16 out (+bias/relu); MODE 1: f32 out via NON-TEMPORAL stores
// (round-6 PMC: the 515 MB logits write stream thrashed L3 -> 4.4x W_U
// re-fetch; nt keeps L3 for the B panels).
// ---------------------------------------------------------------------------
template<int MODE, bool BIAS, bool RELU>
__global__ __launch_bounds__(512, 1)
void gemm256(const bf16_t* __restrict__ A, const bf16_t* __restrict__ Bm,
             char* __restrict__ Out, int ldc,
             const float* __restrict__ bias, int K)
{
    const int mb = blockIdx.x, nb = blockIdx.y;

    __shared__ alignas(16) bf16_t lds[2][2][2][128*64];

    const int tid  = threadIdx.x;
    const int wave = tid >> 6, lane = tid & 63;
    const int wm = wave >> 2, wn = wave & 3;
    const int l16 = lane & 15, lh = lane >> 4;

    const bf16_t* Abase = A  + (long)(mb*256)*K;
    const bf16_t* Bbase = Bm + (long)(nb*256)*K;

    const int c0 = tid,       r0 = c0 >> 3, lc0 = (c0 & 7) ^ (r0 & 7);
    const int c1 = 512 + tid, r1 = c1 >> 3, lc1 = (c1 & 7) ^ (r1 & 7);

    auto stage = [&](int buf, int mat, int half, int k0) {
        const bf16_t* src = (mat ? Bbase : Abase) + (long)(half*128)*K + k0;
        bf16_t* dst = &lds[buf][mat][half][0];
        gload16(&src[(long)r0*K + lc0*8], dst + c0*8);
        gload16(&src[(long)r1*K + lc1*8], dst + c1*8);
    };

    f32x4 acc[8][4];
#pragma unroll
    for (int i=0;i<8;i++)
#pragma unroll
        for (int j=0;j<4;j++) { f32x4 zv={0.f,0.f,0.f,0.f}; acc[i][j]=zv; }

    const int NT = K >> 6;
    stage(0,0,0,0); stage(0,0,1,0); stage(0,1,0,0); stage(0,1,1,0);

    int cur = 0;
    for (int kt = 0; kt < NT; ++kt) {
        const int nxt = cur ^ 1;
        const int k1 = (kt+1) << 6;
        const bool more = (kt+1 < NT);

        if (more) {
            stage(nxt,0,0,k1);
            asm volatile("s_waitcnt vmcnt(2)" ::: "memory");
        } else {
            asm volatile("s_waitcnt vmcnt(0)" ::: "memory");
        }
        asm volatile("s_barrier" ::: "memory");

        bf16x8 af[4][2], bfr[4][2];
#pragma unroll
        for (int i=0;i<4;i++) {
            int ra = i*16 + l16;
#pragma unroll
            for (int kk=0;kk<2;kk++)
                af[i][kk] = *(const bf16x8*)&lds[cur][0][wm][ra*64 + (((kk*4+lh)^(ra&7))*8)];
        }
#pragma unroll
        for (int j=0;j<2;j++) {
            int rb = (wn&1)*64 + j*16 + l16;
#pragma unroll
            for (int kk=0;kk<2;kk++)
                bfr[j][kk] = *(const bf16x8*)&lds[cur][1][wn>>1][rb*64 + (((kk*4+lh)^(rb&7))*8)];
        }
        __builtin_amdgcn_s_setprio(1);
#pragma unroll
        for (int kk=0;kk<2;kk++)
#pragma unroll
            for (int i=0;i<4;i++)
#pragma unroll
                for (int j=0;j<2;j++)
                    acc[i][j] = __builtin_amdgcn_mfma_f32_16x16x32_bf16(af[i][kk], bfr[j][kk], acc[i][j], 0,0,0);
        __builtin_amdgcn_s_setprio(0);

        if (more) stage(nxt,0,1,k1);
#pragma unroll
        for (int j=2;j<4;j++) {
            int rb = (wn&1)*64 + j*16 + l16;
#pragma unroll
            for (int kk=0;kk<2;kk++)
                bfr[j][kk] = *(const bf16x8*)&lds[cur][1][wn>>1][rb*64 + (((kk*4+lh)^(rb&7))*8)];
        }
        __builtin_amdgcn_s_setprio(1);
#pragma unroll
        for (int kk=0;kk<2;kk++)
#pragma unroll
            for (int i=0;i<4;i++)
#pragma unroll
                for (int j=2;j<4;j++)
                    acc[i][j] = __builtin_amdgcn_mfma_f32_16x16x32_bf16(af[i][kk], bfr[j][kk], acc[i][j], 0,0,0);
        __builtin_amdgcn_s_setprio(0);

        if (more) stage(nxt,1,0,k1);
#pragma unroll
        for (int i=0;i<4;i++) {
            int ra = (i+4)*16 + l16;
#pragma unroll
            for (int kk=0;kk<2;kk++)
                af[i][kk] = *(const bf16x8*)&lds[cur][0][wm][ra*64 + (((kk*4+lh)^(ra&7))*8)];
        }
        __builtin_amdgcn_s_setprio(1);
#pragma unroll
        for (int kk=0;kk<2;kk++)
#pragma unroll
            for (int i=0;i<4;i++)
#pragma unroll
                for (int j=0;j<2;j++)
                    acc[i+4][j] = __builtin_amdgcn_mfma_f32_16x16x32_bf16(af[i][kk], bfr[j][kk], acc[i+4][j], 0,0,0);
        __builtin_amdgcn_s_setprio(0);

        if (more) stage(nxt,1,1,k1);
        __builtin_amdgcn_s_setprio(1);
#pragma unroll
        for (int kk=0;kk<2;kk++)
#pragma unroll
            for (int i=0;i<4;i++)
#pragma unroll
                for (int j=2;j<4;j++)
                    acc[i+4][j] = __builtin_amdgcn_mfma_f32_16x16x32_bf16(af[i][kk], bfr[j][kk], acc[i+4][j], 0,0,0);
        __builtin_amdgcn_s_setprio(0);

        asm volatile("s_barrier" ::: "memory");
        cur = nxt;
    }

#pragma unroll
    for (int i=0;i<8;i++) {
        int row0 = mb*256 + wm*128 + i*16 + lh*4;
#pragma unroll
        for (int j=0;j<4;j++) {
            int col = nb*256 + wn*64 + j*16 + l16;
            float bv = BIAS ? bias[col] : 0.0f;
#pragma unroll
            for (int r=0;r<4;r++) {
                int row = row0 + r;
                float v = acc[i][j][r] + bv;
                if (RELU) v = v > 0.f ? v : 0.f;
                if constexpr (MODE == 0)
                    ((bf16_t*)Out)[(long)row*ldc + col] = (bf16_t)v;
                else
                    __builtin_nontemporal_store(v, &((float*)Out)[(long)row*ldc + col]);
            }
        }
    }
}

// ---------------------------------------------------------------------------
// 128-class TN GEMM (N=1024 ops). MODE 0: bf16 (+bias/relu); MODE 1: f32;
// MODE 2: resid_f32 += acc(+bias); residb_bf16 = bf16(resid).
// ---------------------------------------------------------------------------
template<int BM, int BN, int MODE, bool BIAS, bool RELU>
__global__ __launch_bounds__(256)
void gemm_tn(const bf16_t* __restrict__ A, long sA,
             const bf16_t* __restrict__ Bm, long sB,
             char* __restrict__ Out, long sC, int ldc,
             const float* __restrict__ bias,
             float* __restrict__ resid, bf16_t* __restrict__ residb,
             int K)
{
    constexpr int BK = 64;
    constexpr int WM = BM/2, WN = BN/2;
    constexpr int FM = WM/16, FN = WN/16;
    constexpr int APASS = (BM*BK)/(256*8);
    constexpr int BPASS = (BN*BK)/(256*8);

    const int mb = blockIdx.x, nb = blockIdx.y;

    __shared__ alignas(16) bf16_t As[BM*BK];
    __shared__ alignas(16) bf16_t Bs[BN*BK];

    const int tid  = threadIdx.x;
    const int wave = tid >> 6, lane = tid & 63;
    const int wm = wave >> 1, wn = wave & 1;
    const int l16 = lane & 15, lh = lane >> 4;
    const long z = blockIdx.z;

    const bf16_t* Ab = A  + z*sA + (long)mb*BM*K;
    const bf16_t* Bb = Bm + z*sB + (long)nb*BN*K;

    f32x4 acc[FM][FN];
#pragma unroll
    for (int i=0;i<FM;i++)
#pragma unroll
        for (int j=0;j<FN;j++) { f32x4 zv = {0.f,0.f,0.f,0.f}; acc[i][j] = zv; }

    for (int k0 = 0; k0 < K; k0 += BK) {
        __syncthreads();
#pragma unroll
        for (int u=0; u<APASS; ++u) {
            int c = u*256 + tid;
            int row = c >> 3, lc = (c & 7) ^ (row & 7);
            gload16(&Ab[(long)row*K + k0 + lc*8], &As[c*8]);
        }
#pragma unroll
        for (int u=0; u<BPASS; ++u) {
            int c = u*256 + tid;
            int row = c >> 3, lc = (c & 7) ^ (row & 7);
            gload16(&Bb[(long)row*K + k0 + lc*8], &Bs[c*8]);
        }
        __syncthreads();

        bf16x8 af[FM][2], bfr[FN][2];
#pragma unroll
        for (int kk=0;kk<2;kk++) {
#pragma unroll
            for (int i=0;i<FM;i++) {
                int row = wm*WM + i*16 + l16;
                int pw = (kk*4 + lh) ^ (row & 7);
                af[i][kk] = *(const bf16x8*)&As[row*BK + pw*8];
            }
#pragma unroll
            for (int j=0;j<FN;j++) {
                int row = wn*WN + j*16 + l16;
                int pw = (kk*4 + lh) ^ (row & 7);
                bfr[j][kk] = *(const bf16x8*)&Bs[row*BK + pw*8];
            }
        }
#pragma unroll
        for (int kk=0;kk<2;kk++)
#pragma unroll
            for (int i=0;i<FM;i++)
#pragma unroll
                for (int j=0;j<FN;j++)
                    acc[i][j] = __builtin_amdgcn_mfma_f32_16x16x32_bf16(af[i][kk], bfr[j][kk], acc[i][j], 0,0,0);
    }

#pragma unroll
    for (int i=0;i<FM;i++) {
        int row0 = mb*BM + wm*WM + i*16 + lh*4;
#pragma unroll
        for (int j=0;j<FN;j++) {
            int col = nb*BN + wn*WN + j*16 + l16;
            float bv = BIAS ? bias[col] : 0.0f;
#pragma unroll
            for (int r=0;r<4;r++) {
                int row = row0 + r;
                float v = acc[i][j][r] + bv;
                if (RELU) v = v > 0.f ? v : 0.f;
                if constexpr (MODE == 0) {
                    long off = z*sC + (long)row*ldc + col;
                    ((bf16_t*)Out)[off] = (bf16_t)v;
                } else if constexpr (MODE == 1) {
                    long off = z*sC + (long)row*ldc + col;
                    ((float*)Out)[off] = v;
                } else {
                    long o2 = (long)row*ldc + col;
                    float nv = resid[o2] + v;
                    resid[o2]  = nv;
                    residb[o2] = (bf16_t)nv;
                }
            }
        }
    }
}

// ---------------------------------------------------------------------------
// Flash attention (causal). Grid: (S/128, BATCH*NH). Unchanged from round 6.
// ---------------------------------------------------------------------------
__global__ __launch_bounds__(256)
void flash_attn(const bf16_t* __restrict__ qkvf,  // [B][S][3072]
                const bf16_t* __restrict__ vtg,   // [BH][DH][S]
                bf16_t* __restrict__ zf)          // [B][S][DM]
{
    const int qt = blockIdx.x;
    const int bh = blockIdx.y;
    const int b  = bh >> 4, hd = bh & 15;

    __shared__ alignas(16) bf16_t Kl[64*64];
    __shared__ alignas(16) bf16_t Vtl[64*64];
    __shared__ alignas(16) bf16_t Pl[4*32*64];

    const int tid = threadIdx.x;
    const int wave = tid >> 6, lane = tid & 63;
    const int l16 = lane & 15, lh = lane >> 4;
    const int wq_lo = qt*128 + wave*32;
    bf16_t* Pw = Pl + wave*32*64;

    bf16x8 qr[2][2];
#pragma unroll
    for (int qf=0; qf<2; qf++) {
        int qg = wq_lo + qf*16 + l16;
#pragma unroll
        for (int dhh=0; dhh<2; dhh++)
            qr[qf][dhh] = *(const bf16x8*)&qkvf[((long)b*S + qg)*3072 + hd*64 + dhh*32 + lh*8];
    }

    f32x4 o[4][2];
#pragma unroll
    for (int d=0; d<4; d++)
#pragma unroll
        for (int qf=0; qf<2; qf++) { f32x4 zv={0.f,0.f,0.f,0.f}; o[d][qf]=zv; }
    float mrun[2] = {-1e30f, -1e30f};
    float lrun[2] = {0.f, 0.f};

    const int nt = 2*(qt+1);
    const float C = 0.125f;

    for (int t = 0; t < nt; ++t) {
        const int kv0 = t*64;
        __syncthreads();
#pragma unroll
        for (int u=0; u<2; ++u) {
            int c = u*256 + tid;
            int row = c >> 3, lc = (c & 7) ^ (row & 7);
            gload16(&qkvf[((long)b*S + kv0 + row)*3072 + 1024 + hd*64 + lc*8], &Kl[c*8]);
        }
#pragma unroll
        for (int u=0; u<2; ++u) {
            int c = u*256 + tid;
            int row = c >> 3, lc = (c & 7) ^ (row & 7);
            gload16(&vtg[((long)bh*DH + row)*S + kv0 + lc*8], &Vtl[c*8]);
        }
        __syncthreads();

        f32x4 s[4][2];
#pragma unroll
        for (int f=0; f<4; f++)
#pragma unroll
            for (int qf=0; qf<2; qf++) { f32x4 zv={0.f,0.f,0.f,0.f}; s[f][qf]=zv; }
        __builtin_amdgcn_s_setprio(1);
#pragma unroll
        for (int f=0; f<4; f++) {
            int krow = f*16 + l16;
#pragma unroll
            for (int dhh=0; dhh<2; dhh++) {
                bf16x8 kfr = *(const bf16x8*)&Kl[krow*64 + (((dhh*4+lh) ^ (krow&7))*8)];
#pragma unroll
                for (int qf=0; qf<2; qf++)
                    s[f][qf] = __builtin_amdgcn_mfma_f32_16x16x32_bf16(kfr, qr[qf][dhh], s[f][qf], 0,0,0);
            }
        }
        __builtin_amdgcn_s_setprio(0);

        const bool needmask = (kv0 + 64 > wq_lo);

#pragma unroll
        for (int qf=0; qf<2; qf++) {
            int qg = wq_lo + qf*16 + l16;
            float pmax = -1e30f;
#pragma unroll
            for (int f=0; f<4; f++)
#pragma unroll
                for (int r=0; r<4; r++) {
                    float sv = s[f][qf][r];
                    if (needmask && (kv0 + f*16 + lh*4 + r > qg)) { sv = -1e30f; s[f][qf][r] = sv; }
                    pmax = fmaxf(pmax, sv);
                }
            pmax = fmaxf(pmax, __shfl_xor(pmax, 16));
            pmax = fmaxf(pmax, __shfl_xor(pmax, 32));
            float mnew = fmaxf(mrun[qf], pmax);
            float corr = __expf((mrun[qf] - mnew)*C);
            mrun[qf] = mnew;
            lrun[qf] *= corr;
#pragma unroll
            for (int d=0; d<4; d++) o[d][qf] *= corr;
            float lsum = 0.f;
            int qloc = qf*16 + l16;
#pragma unroll
            for (int f=0; f<4; f++) {
                ushort4 pk;
                float p0 = __expf((s[f][qf][0]-mnew)*C);
                float p1 = __expf((s[f][qf][1]-mnew)*C);
                float p2 = __expf((s[f][qf][2]-mnew)*C);
                float p3 = __expf((s[f][qf][3]-mnew)*C);
                lsum += (p0+p1) + (p2+p3);
                pk.x = bfbits(p0); pk.y = bfbits(p1); pk.z = bfbits(p2); pk.w = bfbits(p3);
                int phys = (f*2 + (lh>>1)) ^ (qloc & 7);
                *(ushort4*)&Pw[qloc*64 + phys*8 + (lh&1)*4] = pk;
            }
            lrun[qf] += lsum;
        }

#pragma unroll
        for (int kh=0; kh<2; kh++) {
            bf16x8 pb[2];
#pragma unroll
            for (int qf=0; qf<2; qf++) {
                int qloc = qf*16 + l16;
                pb[qf] = *(const bf16x8*)&Pw[qloc*64 + (((kh*4+lh) ^ (qloc&7))*8)];
            }
            __builtin_amdgcn_s_setprio(1);
#pragma unroll
            for (int d=0; d<4; d++) {
                int vrow = d*16 + l16;
                bf16x8 va = *(const bf16x8*)&Vtl[vrow*64 + (((kh*4+lh) ^ (vrow&7))*8)];
#pragma unroll
                for (int qf=0; qf<2; qf++)
                    o[d][qf] = __builtin_amdgcn_mfma_f32_16x16x32_bf16(va, pb[qf], o[d][qf], 0,0,0);
            }
            __builtin_amdgcn_s_setprio(0);
        }
    }

#pragma unroll
    for (int qf=0; qf<2; qf++) {
        float lt = lrun[qf];
        lt += __shfl_xor(lt, 16);
        lt += __shfl_xor(lt, 32);
        float inv = 1.0f / lt;
        int qg = wq_lo + qf*16 + l16;
#pragma unroll
        for (int d=0; d<4; d++) {
            ushort4 ov;
            ov.x = bfbits(o[d][qf][0]*inv);
            ov.y = bfbits(o[d][qf][1]*inv);
            ov.z = bfbits(o[d][qf][2]*inv);
            ov.w = bfbits(o[d][qf][3]*inv);
            *(ushort4*)&zf[((long)b*S + qg)*DM + hd*64 + d*16 + lh*4] = ov;
        }
    }
}

// ---------------------------------------------------------------------------
// Weight conversion kernels
// ---------------------------------------------------------------------------
__global__ __launch_bounds__(256) void k_conv_qkv(
    const float* __restrict__ Wq, const float* __restrict__ Wk,
    const float* __restrict__ Wv, bf16_t* __restrict__ out)
{
    long idx = (long)blockIdx.x*256 + threadIdx.x;
    long l = idx / (3072L*DM);
    long r = idx % (3072L*DM);
    int row = (int)(r / DM), d = (int)(r % DM);
    int sel = row >> 10, rr = row & 1023;
    const float* src = sel==0 ? Wq : (sel==1 ? Wk : Wv);
    out[idx] = (bf16_t)src[(l*1024 + rr)*(long)DM + d];
}

__global__ __launch_bounds__(256) void k_conv(const float* __restrict__ src,
                                              bf16_t* __restrict__ dst, long n)
{
    long i = ((long)blockIdx.x*256 + threadIdx.x)*4;
    if (i >= n) return;
    float4 v = *(const float4*)&src[i];
    dst[i+0]=(bf16_t)v.x; dst[i+1]=(bf16_t)v.y; dst[i+2]=(bf16_t)v.z; dst[i+3]=(bf16_t)v.w;
}

// W [DM][NC] f32 -> out [NC][DM] bf16 (tiled transpose; W_U and W_E)
__global__ __launch_bounds__(256) void k_trans(const float* __restrict__ W,
                                               bf16_t* __restrict__ out, int NC)
{
    __shared__ float tile[32][33];
    int n0 = blockIdx.x*32, k0 = blockIdx.y*32;
    int tx = threadIdx.x & 31, ty = threadIdx.x >> 5;
#pragma unroll
    for (int u=0;u<4;u++)
        tile[ty+u*8][tx] = W[(long)(k0+ty+u*8)*NC + n0+tx];
    __syncthreads();
#pragma unroll
    for (int u=0;u<4;u++)
        out[(long)(n0+ty+u*8)*DM + k0+tx] = (bf16_t)tile[tx][ty+u*8];
}

// ---------------------------------------------------------------------------
// Embedding from TRANSPOSED W_E: x[b,p,:] = WEt[tok[b,p],:] + W_pos[p,:]
// Coalesced 2KB-row gather (was: 128KB-stride column gather).
// ---------------------------------------------------------------------------
__global__ __launch_bounds__(256) void k_embed(const int* __restrict__ tok,
    const bf16_t* __restrict__ WEt, const float* __restrict__ Wpos,
    float* __restrict__ xf, bf16_t* __restrict__ xb)
{
    int bp = blockIdx.x;
    int p  = bp & (S-1);
    int t  = tok[bp];
    int d  = threadIdx.x*4;
    ushort4 e = *(const ushort4*)&WEt[(long)t*DM + d];
    float4  w = *(const float4*)&Wpos[(long)p*DM + d];
    float4 v;
    v.x = b2f(e.x)+w.x; v.y = b2f(e.y)+w.y; v.z = b2f(e.z)+w.z; v.w = b2f(e.w)+w.w;
    *(float4*)&xf[(long)bp*DM + d] = v;
    ushort4 o;
    o.x = bfbits(v.x); o.y = bfbits(v.y); o.z = bfbits(v.z); o.w = bfbits(v.w);
    *(ushort4*)&xb[(long)bp*DM + d] = o;
}

// qkv_flat V-part -> vT[b,h,dh,p], LDS-tiled transpose (coalesced both sides)
// Grid: (S/64, BATCH*NH), 256 threads.
__global__ __launch_bounds__(256) void k_permv(const bf16_t* __restrict__ qkv,
    bf16_t* __restrict__ vt)
{
    __shared__ bf16_t tile[64][66];
    const int p0 = blockIdx.x*64;
    const int bh = blockIdx.y;
    const int b  = bh >> 4, hd = bh & 15;
    const int tx = threadIdx.x & 63, ty = threadIdx.x >> 6;
#pragma unroll
    for (int u=0;u<16;u++) {
        int r = u*4 + ty;   // token row
        tile[r][tx] = qkv[((long)b*S + p0 + r)*3072 + 2048 + hd*64 + tx];
    }
    __syncthreads();
#pragma unroll
    for (int u=0;u<16;u++) {
        int hh = u*4 + ty;  // dh row
        vt[(((long)bh)*DH + hh)*S + p0 + tx] = tile[tx][hh];
    }
}

// ---------------------------------------------------------------------------
extern "C" void kernel_launch(void* const* d_in, const int* in_sizes, int n_in,
                              void* d_out, int out_size, void* d_ws, size_t ws_size,
                              hipStream_t stream)
{
    const int*   tokens = (const int*)d_in[0];
    const float* W_E    = (const float*)d_in[1];
    const float* W_pos  = (const float*)d_in[2];
    const float* W_K    = (const float*)d_in[3];
    const float* W_Q    = (const float*)d_in[4];
    const float* W_V    = (const float*)d_in[5];
    const float* W_O    = (const float*)d_in[6];
    const float* W_in   = (const float*)d_in[7];
    const float* b_in   = (const float*)d_in[8];
    const float* W_out  = (const float*)d_in[9];
    const float* b_out  = (const float*)d_in[10];
    const float* W_U    = (const float*)d_in[11];
    float* out = (float*)d_out;

    char* ws = (char*)d_ws;
    long off = 0;
    auto alloc = [&](long bytes)->char* {
        char* p = ws + off; off += (bytes + 255) & ~255L; return p;
    };
    bf16_t* wqkv = (bf16_t*)alloc((long)NL*3072*DM*2);
    bf16_t* wo   = (bf16_t*)alloc((long)NL*DM*DM*2);
    bf16_t* win  = (bf16_t*)alloc((long)NL*DMLP*DM*2);
    bf16_t* wout = (bf16_t*)alloc((long)NL*DM*DMLP*2);
    bf16_t* wut  = (bf16_t*)alloc((long)DV*DM*2);
    bf16_t* wet  = (bf16_t*)alloc((long)DV*DM*2);
    float*  xf   = (float*)alloc((long)MTOK*DM*4);
    bf16_t* xb   = (bf16_t*)alloc((long)MTOK*DM*2);
    bf16_t* qkvf = (bf16_t*)alloc((long)MTOK*3072*2);
    bf16_t* vt   = (bf16_t*)alloc((long)BATCH*NH*S*DH*2);
    bf16_t* zf   = (bf16_t*)alloc((long)MTOK*DM*2);
    bf16_t* post = (bf16_t*)alloc((long)MTOK*DMLP*2);

    // --- weight conversion (per launch; deterministic) ---
    k_conv_qkv<<<(int)(((long)NL*3072*DM)/256), 256, 0, stream>>>(W_Q, W_K, W_V, wqkv);
    k_conv<<<(int)(((long)NL*DM*DM)/1024),   256, 0, stream>>>(W_O,   wo,   (long)NL*DM*DM);
    k_conv<<<(int)(((long)NL*DMLP*DM)/1024), 256, 0, stream>>>(W_in,  win,  (long)NL*DMLP*DM);
    k_conv<<<(int)(((long)NL*DM*DMLP)/1024), 256, 0, stream>>>(W_out, wout, (long)NL*DM*DMLP);
    k_trans<<<dim3(DV/32, DM/32), 256, 0, stream>>>(W_U, wut, DV);
    k_trans<<<dim3(DV/32, DM/32), 256, 0, stream>>>(W_E, wet, DV);

    // --- embed (coalesced row gather from transposed W_E) ---
    k_embed<<<MTOK, 256, 0, stream>>>(tokens, wet, W_pos, xf, xb);

    for (int l = 0; l < NL; ++l) {
        // QKV (fused N=3072): 256x256 pipelined kernel
        gemm256<0,false,false><<<dim3(MTOK/256, 3072/256), 512, 0, stream>>>(
            xb, wqkv + (long)l*3072*DM, (char*)qkvf, 3072, nullptr, DM);
        k_permv<<<dim3(S/64, BATCH*NH), 256, 0, stream>>>(qkvf, vt);

        // fused causal attention -> z_flat
        flash_attn<<<dim3(S/128, BATCH*NH), 256, 0, stream>>>(qkvf, vt, zf);

        // attn_out = z_flat @ W_O^T, fused residual add into x (128x128)
        gemm_tn<128,128,2,false,false><<<dim3(MTOK/128, DM/128, 1), 256, 0, stream>>>(
            zf, 0L, wo + (long)l*DM*DM, 0L, nullptr, 0L, DM,
            nullptr, xf, xb, DM);
        // MLP in: relu(x @ W_in^T + b_in): 256x256 pipelined kernel
        gemm256<0,true,true><<<dim3(MTOK/256, DMLP/256), 512, 0, stream>>>(
            xb, win + (long)l*DMLP*DM, (char*)post, DMLP,
            b_in + (long)l*DMLP, DM);
        // MLP out + b_out, fused residual add into x (128x128)
        gemm_tn<128,128,2,true,false><<<dim3(MTOK/128, DM/128, 1), 256, 0, stream>>>(
            post, 0L, wout + (long)l*DM*DMLP, 0L, nullptr, 0L, DM,
            b_out + (long)l*DM, xf, xb, DMLP);
    }

    // logits = x @ W_U (f32 out, non-temporal stores)
    gemm256<1,false,false><<<dim3(MTOK/256, DV/256), 512, 0, stream>>>(
        xb, wut, (char*)out, DV, nullptr, DM);
}

// Round 10
// 1650.628 us; speedup vs baseline: 1.0280x; 1.0280x over previous
//
#include <hip/hip_runtime.h>
#include <hip/hip_bf16.h>
#include <math.h>

// Model dims
#define DV   32000
#define DM   1024
#define DMLP 4096
#define DH   64
#define NH   16
#define NL   4
#define BATCH 2
#define S    2048
#define MTOK (BATCH*S)   // 4096 tokens

typedef __bf16 bf16_t;
typedef bf16_t bf16x8 __attribute__((ext_vector_type(8)));
typedef float  f32x4  __attribute__((ext_vector_type(4)));

#define AS1 __attribute__((address_space(1)))
#define AS3 __attribute__((address_space(3)))

__device__ __forceinline__ void gload16(const bf16_t* g, bf16_t* l) {
    __builtin_amdgcn_global_load_lds((const AS1 void*)g, (AS3 void*)l, 16, 0, 0);
}

__device__ __forceinline__ unsigned short bfbits(float v) {
    union { bf16_t b; unsigned short u; } c; c.b = (bf16_t)v; return c.u;
}
__device__ __forceinline__ float b2f(unsigned short u) {
    union { float f; unsigned v; } c; c.v = ((unsigned)u) << 16; return c.f;
}

// ---------------------------------------------------------------------------
// 256x256 deep-pipelined TN GEMM: C[M,N] = A[M,K] * B[N,K]^T.
// 512 threads = 8 waves (2M x 4N); per-wave output 128x64 (acc[8][4]).
// LDS 128 KiB: [2 buf][A,B][2 half][128x64 bf16], chunk-XOR swizzled.
// Counted vmcnt(2) (never 0 in-loop), 4 phases/K-tile each = 1 half-tile
// prefetch + 16-MFMA setprio cluster.
// MODE 0: bf16 out (+bias/relu), scalar stores (small L3-resident buffers).
// MODE 1: f32 out via LDS-transposed FULL-LINE float4 nontemporal stores.
//   Round-7 lesson: nt on scalar 4B stores bypasses L2 combining -> partial
//   -line writes, WRITE 515->713MB, dur +56us. With 16 lanes x float4 = 256B
//   contiguous per instruction (full lines), nt cannot amplify, and it keeps
//   the 515MB logits stream from evicting W_U panels out of L3.
// ---------------------------------------------------------------------------
template<int MODE, bool BIAS, bool RELU>
__global__ __launch_bounds__(512, 1)
void gemm256(const bf16_t* __restrict__ A, const bf16_t* __restrict__ Bm,
             char* __restrict__ Out, int ldc,
             const float* __restrict__ bias, int K)
{
    const int mb = blockIdx.x, nb = blockIdx.y;

    __shared__ alignas(16) bf16_t lds[2][2][2][128*64];

    const int tid  = threadIdx.x;
    const int wave = tid >> 6, lane = tid & 63;
    const int wm = wave >> 2, wn = wave & 3;
    const int l16 = lane & 15, lh = lane >> 4;

    const bf16_t* Abase = A  + (long)(mb*256)*K;
    const bf16_t* Bbase = Bm + (long)(nb*256)*K;

    const int c0 = tid,       r0 = c0 >> 3, lc0 = (c0 & 7) ^ (r0 & 7);
    const int c1 = 512 + tid, r1 = c1 >> 3, lc1 = (c1 & 7) ^ (r1 & 7);

    auto stage = [&](int buf, int mat, int half, int k0) {
        const bf16_t* src = (mat ? Bbase : Abase) + (long)(half*128)*K + k0;
        bf16_t* dst = &lds[buf][mat][half][0];
        gload16(&src[(long)r0*K + lc0*8], dst + c0*8);
        gload16(&src[(long)r1*K + lc1*8], dst + c1*8);
    };

    f32x4 acc[8][4];
#pragma unroll
    for (int i=0;i<8;i++)
#pragma unroll
        for (int j=0;j<4;j++) { f32x4 zv={0.f,0.f,0.f,0.f}; acc[i][j]=zv; }

    const int NT = K >> 6;
    stage(0,0,0,0); stage(0,0,1,0); stage(0,1,0,0); stage(0,1,1,0);

    int cur = 0;
    for (int kt = 0; kt < NT; ++kt) {
        const int nxt = cur ^ 1;
        const int k1 = (kt+1) << 6;
        const bool more = (kt+1 < NT);

        if (more) {
            stage(nxt,0,0,k1);
            asm volatile("s_waitcnt vmcnt(2)" ::: "memory");
        } else {
            asm volatile("s_waitcnt vmcnt(0)" ::: "memory");
        }
        asm volatile("s_barrier" ::: "memory");

        bf16x8 af[4][2], bfr[4][2];
#pragma unroll
        for (int i=0;i<4;i++) {
            int ra = i*16 + l16;
#pragma unroll
            for (int kk=0;kk<2;kk++)
                af[i][kk] = *(const bf16x8*)&lds[cur][0][wm][ra*64 + (((kk*4+lh)^(ra&7))*8)];
        }
#pragma unroll
        for (int j=0;j<2;j++) {
            int rb = (wn&1)*64 + j*16 + l16;
#pragma unroll
            for (int kk=0;kk<2;kk++)
                bfr[j][kk] = *(const bf16x8*)&lds[cur][1][wn>>1][rb*64 + (((kk*4+lh)^(rb&7))*8)];
        }
        __builtin_amdgcn_s_setprio(1);
#pragma unroll
        for (int kk=0;kk<2;kk++)
#pragma unroll
            for (int i=0;i<4;i++)
#pragma unroll
                for (int j=0;j<2;j++)
                    acc[i][j] = __builtin_amdgcn_mfma_f32_16x16x32_bf16(af[i][kk], bfr[j][kk], acc[i][j], 0,0,0);
        __builtin_amdgcn_s_setprio(0);

        if (more) stage(nxt,0,1,k1);
#pragma unroll
        for (int j=2;j<4;j++) {
            int rb = (wn&1)*64 + j*16 + l16;
#pragma unroll
            for (int kk=0;kk<2;kk++)
                bfr[j][kk] = *(const bf16x8*)&lds[cur][1][wn>>1][rb*64 + (((kk*4+lh)^(rb&7))*8)];
        }
        __builtin_amdgcn_s_setprio(1);
#pragma unroll
        for (int kk=0;kk<2;kk++)
#pragma unroll
            for (int i=0;i<4;i++)
#pragma unroll
                for (int j=2;j<4;j++)
                    acc[i][j] = __builtin_amdgcn_mfma_f32_16x16x32_bf16(af[i][kk], bfr[j][kk], acc[i][j], 0,0,0);
        __builtin_amdgcn_s_setprio(0);

        if (more) stage(nxt,1,0,k1);
#pragma unroll
        for (int i=0;i<4;i++) {
            int ra = (i+4)*16 + l16;
#pragma unroll
            for (int kk=0;kk<2;kk++)
                af[i][kk] = *(const bf16x8*)&lds[cur][0][wm][ra*64 + (((kk*4+lh)^(ra&7))*8)];
        }
        __builtin_amdgcn_s_setprio(1);
#pragma unroll
        for (int kk=0;kk<2;kk++)
#pragma unroll
            for (int i=0;i<4;i++)
#pragma unroll
                for (int j=0;j<2;j++)
                    acc[i+4][j] = __builtin_amdgcn_mfma_f32_16x16x32_bf16(af[i][kk], bfr[j][kk], acc[i+4][j], 0,0,0);
        __builtin_amdgcn_s_setprio(0);

        if (more) stage(nxt,1,1,k1);
        __builtin_amdgcn_s_setprio(1);
#pragma unroll
        for (int kk=0;kk<2;kk++)
#pragma unroll
            for (int i=0;i<4;i++)
#pragma unroll
                for (int j=2;j<4;j++)
                    acc[i+4][j] = __builtin_amdgcn_mfma_f32_16x16x32_bf16(af[i][kk], bfr[j][kk], acc[i+4][j], 0,0,0);
        __builtin_amdgcn_s_setprio(0);

        asm volatile("s_barrier" ::: "memory");
        cur = nxt;
    }

    if constexpr (MODE == 1) {
        // LDS-transposed full-line epilogue. Per-wave slice 32x68 f32
        // (68 stride: 16B-aligned rows, 2-way-max write conflicts).
        // All waves passed the final barrier -> LDS is free to reuse.
        // Wave-internal ds_write->ds_read transpose: lockstep instruction
        // stream + compiler lgkmcnt ordering, no barrier needed.
        float* lsl = reinterpret_cast<float*>(&lds[0][0][0][0]) + wave*(32*68);
        const int lrow = lane >> 4;      // 0..3
        const int lcq  = lane & 15;      // 0..15
#pragma unroll
        for (int ch=0; ch<4; ++ch) {     // 4 chunks of 32 rows
#pragma unroll
            for (int il=0; il<2; ++il)
#pragma unroll
                for (int j=0;j<4;j++)
#pragma unroll
                    for (int r=0;r<4;r++)
                        lsl[(il*16 + lh*4 + r)*68 + j*16 + l16] = acc[ch*2+il][j][r];
#pragma unroll
            for (int u=0; u<8; ++u) {
                int rl = u*4 + lrow;
                f32x4 v = *(const f32x4*)&lsl[rl*68 + lcq*4];
                long row = mb*256 + wm*128 + ch*32 + rl;
                long col = nb*256 + wn*64 + lcq*4;
                __builtin_nontemporal_store(v, (f32x4*)&((float*)Out)[row*ldc + col]);
            }
        }
    } else {
#pragma unroll
        for (int i=0;i<8;i++) {
            int row0 = mb*256 + wm*128 + i*16 + lh*4;
#pragma unroll
            for (int j=0;j<4;j++) {
                int col = nb*256 + wn*64 + j*16 + l16;
                float bv = BIAS ? bias[col] : 0.0f;
#pragma unroll
                for (int r=0;r<4;r++) {
                    int row = row0 + r;
                    float v = acc[i][j][r] + bv;
                    if (RELU) v = v > 0.f ? v : 0.f;
                    ((bf16_t*)Out)[(long)row*ldc + col] = (bf16_t)v;
                }
            }
        }
    }
}

// ---------------------------------------------------------------------------
// 128-class TN GEMM (N=1024 ops). MODE 0: bf16 (+bias/relu); MODE 1: f32;
// MODE 2: resid_f32 += acc(+bias); residb_bf16 = bf16(resid).
// ---------------------------------------------------------------------------
template<int BM, int BN, int MODE, bool BIAS, bool RELU>
__global__ __launch_bounds__(256)
void gemm_tn(const bf16_t* __restrict__ A, long sA,
             const bf16_t* __restrict__ Bm, long sB,
             char* __restrict__ Out, long sC, int ldc,
             const float* __restrict__ bias,
             float* __restrict__ resid, bf16_t* __restrict__ residb,
             int K)
{
    constexpr int BK = 64;
    constexpr int WM = BM/2, WN = BN/2;
    constexpr int FM = WM/16, FN = WN/16;
    constexpr int APASS = (BM*BK)/(256*8);
    constexpr int BPASS = (BN*BK)/(256*8);

    const int mb = blockIdx.x, nb = blockIdx.y;

    __shared__ alignas(16) bf16_t As[BM*BK];
    __shared__ alignas(16) bf16_t Bs[BN*BK];

    const int tid  = threadIdx.x;
    const int wave = tid >> 6, lane = tid & 63;
    const int wm = wave >> 1, wn = wave & 1;
    const int l16 = lane & 15, lh = lane >> 4;
    const long z = blockIdx.z;

    const bf16_t* Ab = A  + z*sA + (long)mb*BM*K;
    const bf16_t* Bb = Bm + z*sB + (long)nb*BN*K;

    f32x4 acc[FM][FN];
#pragma unroll
    for (int i=0;i<FM;i++)
#pragma unroll
        for (int j=0;j<FN;j++) { f32x4 zv = {0.f,0.f,0.f,0.f}; acc[i][j] = zv; }

    for (int k0 = 0; k0 < K; k0 += BK) {
        __syncthreads();
#pragma unroll
        for (int u=0; u<APASS; ++u) {
            int c = u*256 + tid;
            int row = c >> 3, lc = (c & 7) ^ (row & 7);
            gload16(&Ab[(long)row*K + k0 + lc*8], &As[c*8]);
        }
#pragma unroll
        for (int u=0; u<BPASS; ++u) {
            int c = u*256 + tid;
            int row = c >> 3, lc = (c & 7) ^ (row & 7);
            gload16(&Bb[(long)row*K + k0 + lc*8], &Bs[c*8]);
        }
        __syncthreads();

        bf16x8 af[FM][2], bfr[FN][2];
#pragma unroll
        for (int kk=0;kk<2;kk++) {
#pragma unroll
            for (int i=0;i<FM;i++) {
                int row = wm*WM + i*16 + l16;
                int pw = (kk*4 + lh) ^ (row & 7);
                af[i][kk] = *(const bf16x8*)&As[row*BK + pw*8];
            }
#pragma unroll
            for (int j=0;j<FN;j++) {
                int row = wn*WN + j*16 + l16;
                int pw = (kk*4 + lh) ^ (row & 7);
                bfr[j][kk] = *(const bf16x8*)&Bs[row*BK + pw*8];
            }
        }
#pragma unroll
        for (int kk=0;kk<2;kk++)
#pragma unroll
            for (int i=0;i<FM;i++)
#pragma unroll
                for (int j=0;j<FN;j++)
                    acc[i][j] = __builtin_amdgcn_mfma_f32_16x16x32_bf16(af[i][kk], bfr[j][kk], acc[i][j], 0,0,0);
    }

#pragma unroll
    for (int i=0;i<FM;i++) {
        int row0 = mb*BM + wm*WM + i*16 + lh*4;
#pragma unroll
        for (int j=0;j<FN;j++) {
            int col = nb*BN + wn*WN + j*16 + l16;
            float bv = BIAS ? bias[col] : 0.0f;
#pragma unroll
            for (int r=0;r<4;r++) {
                int row = row0 + r;
                float v = acc[i][j][r] + bv;
                if (RELU) v = v > 0.f ? v : 0.f;
                if constexpr (MODE == 0) {
                    long off = z*sC + (long)row*ldc + col;
                    ((bf16_t*)Out)[off] = (bf16_t)v;
                } else if constexpr (MODE == 1) {
                    long off = z*sC + (long)row*ldc + col;
                    ((float*)Out)[off] = v;
                } else {
                    long o2 = (long)row*ldc + col;
                    float nv = resid[o2] + v;
                    resid[o2]  = nv;
                    residb[o2] = (bf16_t)nv;
                }
            }
        }
    }
}

// ---------------------------------------------------------------------------
// Flash attention (causal). Grid: (S/128, BATCH*NH). Unchanged.
// ---------------------------------------------------------------------------
__global__ __launch_bounds__(256)
void flash_attn(const bf16_t* __restrict__ qkvf,  // [B][S][3072]
                const bf16_t* __restrict__ vtg,   // [BH][DH][S]
                bf16_t* __restrict__ zf)          // [B][S][DM]
{
    const int qt = blockIdx.x;
    const int bh = blockIdx.y;
    const int b  = bh >> 4, hd = bh & 15;

    __shared__ alignas(16) bf16_t Kl[64*64];
    __shared__ alignas(16) bf16_t Vtl[64*64];
    __shared__ alignas(16) bf16_t Pl[4*32*64];

    const int tid = threadIdx.x;
    const int wave = tid >> 6, lane = tid & 63;
    const int l16 = lane & 15, lh = lane >> 4;
    const int wq_lo = qt*128 + wave*32;
    bf16_t* Pw = Pl + wave*32*64;

    bf16x8 qr[2][2];
#pragma unroll
    for (int qf=0; qf<2; qf++) {
        int qg = wq_lo + qf*16 + l16;
#pragma unroll
        for (int dhh=0; dhh<2; dhh++)
            qr[qf][dhh] = *(const bf16x8*)&qkvf[((long)b*S + qg)*3072 + hd*64 + dhh*32 + lh*8];
    }

    f32x4 o[4][2];
#pragma unroll
    for (int d=0; d<4; d++)
#pragma unroll
        for (int qf=0; qf<2; qf++) { f32x4 zv={0.f,0.f,0.f,0.f}; o[d][qf]=zv; }
    float mrun[2] = {-1e30f, -1e30f};
    float lrun[2] = {0.f, 0.f};

    const int nt = 2*(qt+1);
    const float C = 0.125f;

    for (int t = 0; t < nt; ++t) {
        const int kv0 = t*64;
        __syncthreads();
#pragma unroll
        for (int u=0; u<2; ++u) {
            int c = u*256 + tid;
            int row = c >> 3, lc = (c & 7) ^ (row & 7);
            gload16(&qkvf[((long)b*S + kv0 + row)*3072 + 1024 + hd*64 + lc*8], &Kl[c*8]);
        }
#pragma unroll
        for (int u=0; u<2; ++u) {
            int c = u*256 + tid;
            int row = c >> 3, lc = (c & 7) ^ (row & 7);
            gload16(&vtg[((long)bh*DH + row)*S + kv0 + lc*8], &Vtl[c*8]);
        }
        __syncthreads();

        f32x4 s[4][2];
#pragma unroll
        for (int f=0; f<4; f++)
#pragma unroll
            for (int qf=0; qf<2; qf++) { f32x4 zv={0.f,0.f,0.f,0.f}; s[f][qf]=zv; }
        __builtin_amdgcn_s_setprio(1);
#pragma unroll
        for (int f=0; f<4; f++) {
            int krow = f*16 + l16;
#pragma unroll
            for (int dhh=0; dhh<2; dhh++) {
                bf16x8 kfr = *(const bf16x8*)&Kl[krow*64 + (((dhh*4+lh) ^ (krow&7))*8)];
#pragma unroll
                for (int qf=0; qf<2; qf++)
                    s[f][qf] = __builtin_amdgcn_mfma_f32_16x16x32_bf16(kfr, qr[qf][dhh], s[f][qf], 0,0,0);
            }
        }
        __builtin_amdgcn_s_setprio(0);

        const bool needmask = (kv0 + 64 > wq_lo);

#pragma unroll
        for (int qf=0; qf<2; qf++) {
            int qg = wq_lo + qf*16 + l16;
            float pmax = -1e30f;
#pragma unroll
            for (int f=0; f<4; f++)
#pragma unroll
                for (int r=0; r<4; r++) {
                    float sv = s[f][qf][r];
                    if (needmask && (kv0 + f*16 + lh*4 + r > qg)) { sv = -1e30f; s[f][qf][r] = sv; }
                    pmax = fmaxf(pmax, sv);
                }
            pmax = fmaxf(pmax, __shfl_xor(pmax, 16));
            pmax = fmaxf(pmax, __shfl_xor(pmax, 32));
            float mnew = fmaxf(mrun[qf], pmax);
            float corr = __expf((mrun[qf] - mnew)*C);
            mrun[qf] = mnew;
            lrun[qf] *= corr;
#pragma unroll
            for (int d=0; d<4; d++) o[d][qf] *= corr;
            float lsum = 0.f;
            int qloc = qf*16 + l16;
#pragma unroll
            for (int f=0; f<4; f++) {
                ushort4 pk;
                float p0 = __expf((s[f][qf][0]-mnew)*C);
                float p1 = __expf((s[f][qf][1]-mnew)*C);
                float p2 = __expf((s[f][qf][2]-mnew)*C);
                float p3 = __expf((s[f][qf][3]-mnew)*C);
                lsum += (p0+p1) + (p2+p3);
                pk.x = bfbits(p0); pk.y = bfbits(p1); pk.z = bfbits(p2); pk.w = bfbits(p3);
                int phys = (f*2 + (lh>>1)) ^ (qloc & 7);
                *(ushort4*)&Pw[qloc*64 + phys*8 + (lh&1)*4] = pk;
            }
            lrun[qf] += lsum;
        }

#pragma unroll
        for (int kh=0; kh<2; kh++) {
            bf16x8 pb[2];
#pragma unroll
            for (int qf=0; qf<2; qf++) {
                int qloc = qf*16 + l16;
                pb[qf] = *(const bf16x8*)&Pw[qloc*64 + (((kh*4+lh) ^ (qloc&7))*8)];
            }
            __builtin_amdgcn_s_setprio(1);
#pragma unroll
            for (int d=0; d<4; d++) {
                int vrow = d*16 + l16;
                bf16x8 va = *(const bf16x8*)&Vtl[vrow*64 + (((kh*4+lh) ^ (vrow&7))*8)];
#pragma unroll
                for (int qf=0; qf<2; qf++)
                    o[d][qf] = __builtin_amdgcn_mfma_f32_16x16x32_bf16(va, pb[qf], o[d][qf], 0,0,0);
            }
            __builtin_amdgcn_s_setprio(0);
        }
    }

#pragma unroll
    for (int qf=0; qf<2; qf++) {
        float lt = lrun[qf];
        lt += __shfl_xor(lt, 16);
        lt += __shfl_xor(lt, 32);
        float inv = 1.0f / lt;
        int qg = wq_lo + qf*16 + l16;
#pragma unroll
        for (int d=0; d<4; d++) {
            ushort4 ov;
            ov.x = bfbits(o[d][qf][0]*inv);
            ov.y = bfbits(o[d][qf][1]*inv);
            ov.z = bfbits(o[d][qf][2]*inv);
            ov.w = bfbits(o[d][qf][3]*inv);
            *(ushort4*)&zf[((long)b*S + qg)*DM + hd*64 + d*16 + lh*4] = ov;
        }
    }
}

// ---------------------------------------------------------------------------
// Weight conversion kernels
// ---------------------------------------------------------------------------
__global__ __launch_bounds__(256) void k_conv_qkv(
    const float* __restrict__ Wq, const float* __restrict__ Wk,
    const float* __restrict__ Wv, bf16_t* __restrict__ out)
{
    long idx = (long)blockIdx.x*256 + threadIdx.x;
    long l = idx / (3072L*DM);
    long r = idx % (3072L*DM);
    int row = (int)(r / DM), d = (int)(r % DM);
    int sel = row >> 10, rr = row & 1023;
    const float* src = sel==0 ? Wq : (sel==1 ? Wk : Wv);
    out[idx] = (bf16_t)src[(l*1024 + rr)*(long)DM + d];
}

__global__ __launch_bounds__(256) void k_conv(const float* __restrict__ src,
                                              bf16_t* __restrict__ dst, long n)
{
    long i = ((long)blockIdx.x*256 + threadIdx.x)*4;
    if (i >= n) return;
    float4 v = *(const float4*)&src[i];
    dst[i+0]=(bf16_t)v.x; dst[i+1]=(bf16_t)v.y; dst[i+2]=(bf16_t)v.z; dst[i+3]=(bf16_t)v.w;
}

// W [DM][NC] f32 -> out [NC][DM] bf16 (tiled transpose; W_U and W_E)
__global__ __launch_bounds__(256) void k_trans(const float* __restrict__ W,
                                               bf16_t* __restrict__ out, int NC)
{
    __shared__ float tile[32][33];
    int n0 = blockIdx.x*32, k0 = blockIdx.y*32;
    int tx = threadIdx.x & 31, ty = threadIdx.x >> 5;
#pragma unroll
    for (int u=0;u<4;u++)
        tile[ty+u*8][tx] = W[(long)(k0+ty+u*8)*NC + n0+tx];
    __syncthreads();
#pragma unroll
    for (int u=0;u<4;u++)
        out[(long)(n0+ty+u*8)*DM + k0+tx] = (bf16_t)tile[tx][ty+u*8];
}

// ---------------------------------------------------------------------------
// Embedding from TRANSPOSED W_E: x[b,p,:] = WEt[tok[b,p],:] + W_pos[p,:]
// ---------------------------------------------------------------------------
__global__ __launch_bounds__(256) void k_embed(const int* __restrict__ tok,
    const bf16_t* __restrict__ WEt, const float* __restrict__ Wpos,
    float* __restrict__ xf, bf16_t* __restrict__ xb)
{
    int bp = blockIdx.x;
    int p  = bp & (S-1);
    int t  = tok[bp];
    int d  = threadIdx.x*4;
    ushort4 e = *(const ushort4*)&WEt[(long)t*DM + d];
    float4  w = *(const float4*)&Wpos[(long)p*DM + d];
    float4 v;
    v.x = b2f(e.x)+w.x; v.y = b2f(e.y)+w.y; v.z = b2f(e.z)+w.z; v.w = b2f(e.w)+w.w;
    *(float4*)&xf[(long)bp*DM + d] = v;
    ushort4 o;
    o.x = bfbits(v.x); o.y = bfbits(v.y); o.z = bfbits(v.z); o.w = bfbits(v.w);
    *(ushort4*)&xb[(long)bp*DM + d] = o;
}

// qkv_flat V-part -> vT[b,h,dh,p], LDS-tiled transpose
__global__ __launch_bounds__(256) void k_permv(const bf16_t* __restrict__ qkv,
    bf16_t* __restrict__ vt)
{
    __shared__ bf16_t tile[64][66];
    const int p0 = blockIdx.x*64;
    const int bh = blockIdx.y;
    const int b  = bh >> 4, hd = bh & 15;
    const int tx = threadIdx.x & 63, ty = threadIdx.x >> 6;
#pragma unroll
    for (int u=0;u<16;u++) {
        int r = u*4 + ty;
        tile[r][tx] = qkv[((long)b*S + p0 + r)*3072 + 2048 + hd*64 + tx];
    }
    __syncthreads();
#pragma unroll
    for (int u=0;u<16;u++) {
        int hh = u*4 + ty;
        vt[(((long)bh)*DH + hh)*S + p0 + tx] = tile[tx][hh];
    }
}

// ---------------------------------------------------------------------------
extern "C" void kernel_launch(void* const* d_in, const int* in_sizes, int n_in,
                              void* d_out, int out_size, void* d_ws, size_t ws_size,
                              hipStream_t stream)
{
    const int*   tokens = (const int*)d_in[0];
    const float* W_E    = (const float*)d_in[1];
    const float* W_pos  = (const float*)d_in[2];
    const float* W_K    = (const float*)d_in[3];
    const float* W_Q    = (const float*)d_in[4];
    const float* W_V    = (const float*)d_in[5];
    const float* W_O    = (const float*)d_in[6];
    const float* W_in   = (const float*)d_in[7];
    const float* b_in   = (const float*)d_in[8];
    const float* W_out  = (const float*)d_in[9];
    const float* b_out  = (const float*)d_in[10];
    const float* W_U    = (const float*)d_in[11];
    float* out = (float*)d_out;

    char* ws = (char*)d_ws;
    long off = 0;
    auto alloc = [&](long bytes)->char* {
        char* p = ws + off; off += (bytes + 255) & ~255L; return p;
    };
    bf16_t* wqkv = (bf16_t*)alloc((long)NL*3072*DM*2);
    bf16_t* wo   = (bf16_t*)alloc((long)NL*DM*DM*2);
    bf16_t* win  = (bf16_t*)alloc((long)NL*DMLP*DM*2);
    bf16_t* wout = (bf16_t*)alloc((long)NL*DM*DMLP*2);
    bf16_t* wut  = (bf16_t*)alloc((long)DV*DM*2);
    bf16_t* wet  = (bf16_t*)alloc((long)DV*DM*2);
    float*  xf   = (float*)alloc((long)MTOK*DM*4);
    bf16_t* xb   = (bf16_t*)alloc((long)MTOK*DM*2);
    bf16_t* qkvf = (bf16_t*)alloc((long)MTOK*3072*2);
    bf16_t* vt   = (bf16_t*)alloc((long)BATCH*NH*S*DH*2);
    bf16_t* zf   = (bf16_t*)alloc((long)MTOK*DM*2);
    bf16_t* post = (bf16_t*)alloc((long)MTOK*DMLP*2);

    // --- weight conversion (per launch; deterministic) ---
    k_conv_qkv<<<(int)(((long)NL*3072*DM)/256), 256, 0, stream>>>(W_Q, W_K, W_V, wqkv);
    k_conv<<<(int)(((long)NL*DM*DM)/1024),   256, 0, stream>>>(W_O,   wo,   (long)NL*DM*DM);
    k_conv<<<(int)(((long)NL*DMLP*DM)/1024), 256, 0, stream>>>(W_in,  win,  (long)NL*DMLP*DM);
    k_conv<<<(int)(((long)NL*DM*DMLP)/1024), 256, 0, stream>>>(W_out, wout, (long)NL*DM*DMLP);
    k_trans<<<dim3(DV/32, DM/32), 256, 0, stream>>>(W_U, wut, DV);
    k_trans<<<dim3(DV/32, DM/32), 256, 0, stream>>>(W_E, wet, DV);

    // --- embed ---
    k_embed<<<MTOK, 256, 0, stream>>>(tokens, wet, W_pos, xf, xb);

    for (int l = 0; l < NL; ++l) {
        // QKV (fused N=3072)
        gemm256<0,false,false><<<dim3(MTOK/256, 3072/256), 512, 0, stream>>>(
            xb, wqkv + (long)l*3072*DM, (char*)qkvf, 3072, nullptr, DM);
        k_permv<<<dim3(S/64, BATCH*NH), 256, 0, stream>>>(qkvf, vt);

        // fused causal attention -> z_flat
        flash_attn<<<dim3(S/128, BATCH*NH), 256, 0, stream>>>(qkvf, vt, zf);

        // attn_out = z_flat @ W_O^T, fused residual add into x
        gemm_tn<128,128,2,false,false><<<dim3(MTOK/128, DM/128, 1), 256, 0, stream>>>(
            zf, 0L, wo + (long)l*DM*DM, 0L, nullptr, 0L, DM,
            nullptr, xf, xb, DM);
        // MLP in: relu(x @ W_in^T + b_in)
        gemm256<0,true,true><<<dim3(MTOK/256, DMLP/256), 512, 0, stream>>>(
            xb, win + (long)l*DMLP*DM, (char*)post, DMLP,
            b_in + (long)l*DMLP, DM);
        // MLP out + b_out, fused residual add into x
        gemm_tn<128,128,2,true,false><<<dim3(MTOK/128, DM/128, 1), 256, 0, stream>>>(
            post, 0L, wout + (long)l*DM*DMLP, 0L, nullptr, 0L, DM,
            b_out + (long)l*DM, xf, xb, DMLP);
    }

    // logits = x @ W_U (f32 out, full-line nt stores)
    gemm256<1,false,false><<<dim3(MTOK/256, DV/256), 512, 0, stream>>>(
        xb, wut, (char*)out, DV, nullptr, DM);
}

// Round 12
// 1589.794 us; speedup vs baseline: 1.0673x; 1.0383x over previous
//
#include <hip/hip_runtime.h>
#include <hip/hip_bf16.h>
#include <math.h>

// Model dims
#define DV   32000
#define DM   1024
#define DMLP 4096
#define DH   64
#define NH   16
#define NL   4
#define BATCH 2
#define S    2048
#define MTOK (BATCH*S)   // 4096 tokens

typedef __bf16 bf16_t;
typedef bf16_t bf16x8 __attribute__((ext_vector_type(8)));
typedef float  f32x4  __attribute__((ext_vector_type(4)));

#define AS1 __attribute__((address_space(1)))
#define AS3 __attribute__((address_space(3)))

__device__ __forceinline__ void gload16(const bf16_t* g, bf16_t* l) {
    __builtin_amdgcn_global_load_lds((const AS1 void*)g, (AS3 void*)l, 16, 0, 0);
}

__device__ __forceinline__ unsigned short bfbits(float v) {
    union { bf16_t b; unsigned short u; } c; c.b = (bf16_t)v; return c.u;
}
__device__ __forceinline__ float b2f(unsigned short u) {
    union { float f; unsigned v; } c; c.v = ((unsigned)u) << 16; return c.f;
}

// ---------------------------------------------------------------------------
// 128x128 double-buffered counted-vmcnt TN GEMM. 256 threads = 4 waves
// (2Mx2N), per-wave 64x64 (acc[4][4]). LDS 64 KiB = [2 buf][A,B][128x64
// bf16] chunk-XOR swizzled -> 2 blocks/CU (16 waves/CU): TLP hides the
// L3/HBM staging latency that capped gemm256 at 36% MfmaUtil (round-10
// diagnosis: 1 block/CU, 600-cyc pipeline < 900-cyc miss latency).
// Per K-tile: phase0 {stage A(next); vmcnt(4); barrier; 16 MFMA},
// phase1 {stage B(next); 16 MFMA}; end barrier. vmcnt never 0 in-loop.
// MODE 0: bf16 out (+bias/relu). MODE 1: f32 out, LDS-transposed full-line
// f32x4 nontemporal stores. MODE 2: resid_f32 += acc(+bias); residb=bf16.
// ---------------------------------------------------------------------------
template<int MODE, bool BIAS, bool RELU>
__global__ __launch_bounds__(256, 2)
void gemm128d(const bf16_t* __restrict__ A, const bf16_t* __restrict__ Bm,
              char* __restrict__ Out, int ldc,
              const float* __restrict__ bias,
              float* __restrict__ resid, bf16_t* __restrict__ residb,
              int K)
{
    const int mb = blockIdx.x, nb = blockIdx.y;

    __shared__ alignas(16) bf16_t lds[2][2][128*64];

    const int tid  = threadIdx.x;
    const int wave = tid >> 6, lane = tid & 63;
    const int wm = wave >> 1, wn = wave & 1;
    const int l16 = lane & 15, lh = lane >> 4;

    const bf16_t* Abase = A  + (long)(mb*128)*K;
    const bf16_t* Bbase = Bm + (long)(nb*128)*K;

    auto stage = [&](int buf, int mat, int k0) {
        const bf16_t* src = (mat ? Bbase : Abase) + k0;
        bf16_t* dst = &lds[buf][mat][0];
#pragma unroll
        for (int u=0; u<4; ++u) {
            int c = u*256 + tid;
            int row = c >> 3, lc = (c & 7) ^ (row & 7);
            gload16(&src[(long)row*K + lc*8], dst + c*8);
        }
    };

    f32x4 acc[4][4];
#pragma unroll
    for (int i=0;i<4;i++)
#pragma unroll
        for (int j=0;j<4;j++) { f32x4 zv={0.f,0.f,0.f,0.f}; acc[i][j]=zv; }

    const int NT = K >> 6;
    stage(0,0,0); stage(0,1,0);

    int cur = 0;
    for (int kt = 0; kt < NT; ++kt) {
        const int nxt = cur ^ 1;
        const int k1 = (kt+1) << 6;
        const bool more = (kt+1 < NT);

        // phase 0: prefetch A(next); counted wait (4 newest = A(next));
        if (more) {
            stage(nxt,0,k1);
            asm volatile("s_waitcnt vmcnt(4)" ::: "memory");
        } else {
            asm volatile("s_waitcnt vmcnt(0)" ::: "memory");
        }
        asm volatile("s_barrier" ::: "memory");

        bf16x8 af[4][2], bfr[4][2];
#pragma unroll
        for (int i=0;i<4;i++) {
            int ra = wm*64 + i*16 + l16;
#pragma unroll
            for (int kk=0;kk<2;kk++)
                af[i][kk] = *(const bf16x8*)&lds[cur][0][ra*64 + (((kk*4+lh)^(ra&7))*8)];
        }
#pragma unroll
        for (int j=0;j<2;j++) {
            int rb = wn*64 + j*16 + l16;
#pragma unroll
            for (int kk=0;kk<2;kk++)
                bfr[j][kk] = *(const bf16x8*)&lds[cur][1][rb*64 + (((kk*4+lh)^(rb&7))*8)];
        }
        __builtin_amdgcn_s_setprio(1);
#pragma unroll
        for (int kk=0;kk<2;kk++)
#pragma unroll
            for (int i=0;i<4;i++)
#pragma unroll
                for (int j=0;j<2;j++)
                    acc[i][j] = __builtin_amdgcn_mfma_f32_16x16x32_bf16(af[i][kk], bfr[j][kk], acc[i][j], 0,0,0);
        __builtin_amdgcn_s_setprio(0);

        // phase 1: prefetch B(next); compute n-half 1
        if (more) stage(nxt,1,k1);
#pragma unroll
        for (int j=2;j<4;j++) {
            int rb = wn*64 + j*16 + l16;
#pragma unroll
            for (int kk=0;kk<2;kk++)
                bfr[j][kk] = *(const bf16x8*)&lds[cur][1][rb*64 + (((kk*4+lh)^(rb&7))*8)];
        }
        __builtin_amdgcn_s_setprio(1);
#pragma unroll
        for (int kk=0;kk<2;kk++)
#pragma unroll
            for (int i=0;i<4;i++)
#pragma unroll
                for (int j=2;j<4;j++)
                    acc[i][j] = __builtin_amdgcn_mfma_f32_16x16x32_bf16(af[i][kk], bfr[j][kk], acc[i][j], 0,0,0);
        __builtin_amdgcn_s_setprio(0);

        asm volatile("s_barrier" ::: "memory");
        cur = nxt;
    }

    if constexpr (MODE == 1) {
        // LDS-transposed full-line f32x4 nt epilogue (per-wave 32x68 slice).
        float* lsl = reinterpret_cast<float*>(&lds[0][0][0]) + wave*(32*68);
        const int lrow = lane >> 4;
        const int lcq  = lane & 15;
#pragma unroll
        for (int ch=0; ch<2; ++ch) {
#pragma unroll
            for (int il=0; il<2; ++il)
#pragma unroll
                for (int j=0;j<4;j++)
#pragma unroll
                    for (int r=0;r<4;r++)
                        lsl[(il*16 + lh*4 + r)*68 + j*16 + l16] = acc[ch*2+il][j][r];
#pragma unroll
            for (int u=0; u<8; ++u) {
                int rl = u*4 + lrow;
                f32x4 v = *(const f32x4*)&lsl[rl*68 + lcq*4];
                long row = mb*128 + wm*64 + ch*32 + rl;
                long col = nb*128 + wn*64 + lcq*4;
                __builtin_nontemporal_store(v, (f32x4*)&((float*)Out)[row*ldc + col]);
            }
        }
    } else {
#pragma unroll
        for (int i=0;i<4;i++) {
            int row0 = mb*128 + wm*64 + i*16 + lh*4;
#pragma unroll
            for (int j=0;j<4;j++) {
                int col = nb*128 + wn*64 + j*16 + l16;
                float bv = BIAS ? bias[col] : 0.0f;
#pragma unroll
                for (int r=0;r<4;r++) {
                    int row = row0 + r;
                    float v = acc[i][j][r] + bv;
                    if (RELU) v = v > 0.f ? v : 0.f;
                    if constexpr (MODE == 0) {
                        ((bf16_t*)Out)[(long)row*ldc + col] = (bf16_t)v;
                    } else {
                        long o2 = (long)row*ldc + col;
                        float nv = resid[o2] + v;
                        resid[o2]  = nv;
                        residb[o2] = (bf16_t)nv;
                    }
                }
            }
        }
    }
}

// ---------------------------------------------------------------------------
// 256x256 deep-pipelined TN GEMM (kept for MLP-in: grid 16x16=256 blocks).
// ---------------------------------------------------------------------------
template<int MODE, bool BIAS, bool RELU>
__global__ __launch_bounds__(512, 1)
void gemm256(const bf16_t* __restrict__ A, const bf16_t* __restrict__ Bm,
             char* __restrict__ Out, int ldc,
             const float* __restrict__ bias, int K)
{
    const int mb = blockIdx.x, nb = blockIdx.y;

    __shared__ alignas(16) bf16_t lds[2][2][2][128*64];

    const int tid  = threadIdx.x;
    const int wave = tid >> 6, lane = tid & 63;
    const int wm = wave >> 2, wn = wave & 3;
    const int l16 = lane & 15, lh = lane >> 4;

    const bf16_t* Abase = A  + (long)(mb*256)*K;
    const bf16_t* Bbase = Bm + (long)(nb*256)*K;

    const int c0 = tid,       r0 = c0 >> 3, lc0 = (c0 & 7) ^ (r0 & 7);
    const int c1 = 512 + tid, r1 = c1 >> 3, lc1 = (c1 & 7) ^ (r1 & 7);

    auto stage = [&](int buf, int mat, int half, int k0) {
        const bf16_t* src = (mat ? Bbase : Abase) + (long)(half*128)*K + k0;
        bf16_t* dst = &lds[buf][mat][half][0];
        gload16(&src[(long)r0*K + lc0*8], dst + c0*8);
        gload16(&src[(long)r1*K + lc1*8], dst + c1*8);
    };

    f32x4 acc[8][4];
#pragma unroll
    for (int i=0;i<8;i++)
#pragma unroll
        for (int j=0;j<4;j++) { f32x4 zv={0.f,0.f,0.f,0.f}; acc[i][j]=zv; }

    const int NT = K >> 6;
    stage(0,0,0,0); stage(0,0,1,0); stage(0,1,0,0); stage(0,1,1,0);

    int cur = 0;
    for (int kt = 0; kt < NT; ++kt) {
        const int nxt = cur ^ 1;
        const int k1 = (kt+1) << 6;
        const bool more = (kt+1 < NT);

        if (more) {
            stage(nxt,0,0,k1);
            asm volatile("s_waitcnt vmcnt(2)" ::: "memory");
        } else {
            asm volatile("s_waitcnt vmcnt(0)" ::: "memory");
        }
        asm volatile("s_barrier" ::: "memory");

        bf16x8 af[4][2], bfr[4][2];
#pragma unroll
        for (int i=0;i<4;i++) {
            int ra = i*16 + l16;
#pragma unroll
            for (int kk=0;kk<2;kk++)
                af[i][kk] = *(const bf16x8*)&lds[cur][0][wm][ra*64 + (((kk*4+lh)^(ra&7))*8)];
        }
#pragma unroll
        for (int j=0;j<2;j++) {
            int rb = (wn&1)*64 + j*16 + l16;
#pragma unroll
            for (int kk=0;kk<2;kk++)
                bfr[j][kk] = *(const bf16x8*)&lds[cur][1][wn>>1][rb*64 + (((kk*4+lh)^(rb&7))*8)];
        }
        __builtin_amdgcn_s_setprio(1);
#pragma unroll
        for (int kk=0;kk<2;kk++)
#pragma unroll
            for (int i=0;i<4;i++)
#pragma unroll
                for (int j=0;j<2;j++)
                    acc[i][j] = __builtin_amdgcn_mfma_f32_16x16x32_bf16(af[i][kk], bfr[j][kk], acc[i][j], 0,0,0);
        __builtin_amdgcn_s_setprio(0);

        if (more) stage(nxt,0,1,k1);
#pragma unroll
        for (int j=2;j<4;j++) {
            int rb = (wn&1)*64 + j*16 + l16;
#pragma unroll
            for (int kk=0;kk<2;kk++)
                bfr[j][kk] = *(const bf16x8*)&lds[cur][1][wn>>1][rb*64 + (((kk*4+lh)^(rb&7))*8)];
        }
        __builtin_amdgcn_s_setprio(1);
#pragma unroll
        for (int kk=0;kk<2;kk++)
#pragma unroll
            for (int i=0;i<4;i++)
#pragma unroll
                for (int j=2;j<4;j++)
                    acc[i][j] = __builtin_amdgcn_mfma_f32_16x16x32_bf16(af[i][kk], bfr[j][kk], acc[i][j], 0,0,0);
        __builtin_amdgcn_s_setprio(0);

        if (more) stage(nxt,1,0,k1);
#pragma unroll
        for (int i=0;i<4;i++) {
            int ra = (i+4)*16 + l16;
#pragma unroll
            for (int kk=0;kk<2;kk++)
                af[i][kk] = *(const bf16x8*)&lds[cur][0][wm][ra*64 + (((kk*4+lh)^(ra&7))*8)];
        }
        __builtin_amdgcn_s_setprio(1);
#pragma unroll
        for (int kk=0;kk<2;kk++)
#pragma unroll
            for (int i=0;i<4;i++)
#pragma unroll
                for (int j=0;j<2;j++)
                    acc[i+4][j] = __builtin_amdgcn_mfma_f32_16x16x32_bf16(af[i][kk], bfr[j][kk], acc[i+4][j], 0,0,0);
        __builtin_amdgcn_s_setprio(0);

        if (more) stage(nxt,1,1,k1);
        __builtin_amdgcn_s_setprio(1);
#pragma unroll
        for (int kk=0;kk<2;kk++)
#pragma unroll
            for (int i=0;i<4;i++)
#pragma unroll
                for (int j=2;j<4;j++)
                    acc[i+4][j] = __builtin_amdgcn_mfma_f32_16x16x32_bf16(af[i][kk], bfr[j][kk], acc[i+4][j], 0,0,0);
        __builtin_amdgcn_s_setprio(0);

        asm volatile("s_barrier" ::: "memory");
        cur = nxt;
    }

#pragma unroll
    for (int i=0;i<8;i++) {
        int row0 = mb*256 + wm*128 + i*16 + lh*4;
#pragma unroll
        for (int j=0;j<4;j++) {
            int col = nb*256 + wn*64 + j*16 + l16;
            float bv = BIAS ? bias[col] : 0.0f;
#pragma unroll
            for (int r=0;r<4;r++) {
                int row = row0 + r;
                float v = acc[i][j][r] + bv;
                if (RELU) v = v > 0.f ? v : 0.f;
                ((bf16_t*)Out)[(long)row*ldc + col] = (bf16_t)v;
            }
        }
    }
}

// ---------------------------------------------------------------------------
// Flash attention (causal). Grid: (S/128, BATCH*NH). Unchanged.
// ---------------------------------------------------------------------------
__global__ __launch_bounds__(256)
void flash_attn(const bf16_t* __restrict__ qkvf,  // [B][S][3072]
                const bf16_t* __restrict__ vtg,   // [BH][DH][S]
                bf16_t* __restrict__ zf)          // [B][S][DM]
{
    const int qt = blockIdx.x;
    const int bh = blockIdx.y;
    const int b  = bh >> 4, hd = bh & 15;

    __shared__ alignas(16) bf16_t Kl[64*64];
    __shared__ alignas(16) bf16_t Vtl[64*64];
    __shared__ alignas(16) bf16_t Pl[4*32*64];

    const int tid = threadIdx.x;
    const int wave = tid >> 6, lane = tid & 63;
    const int l16 = lane & 15, lh = lane >> 4;
    const int wq_lo = qt*128 + wave*32;
    bf16_t* Pw = Pl + wave*32*64;

    bf16x8 qr[2][2];
#pragma unroll
    for (int qf=0; qf<2; qf++) {
        int qg = wq_lo + qf*16 + l16;
#pragma unroll
        for (int dhh=0; dhh<2; dhh++)
            qr[qf][dhh] = *(const bf16x8*)&qkvf[((long)b*S + qg)*3072 + hd*64 + dhh*32 + lh*8];
    }

    f32x4 o[4][2];
#pragma unroll
    for (int d=0; d<4; d++)
#pragma unroll
        for (int qf=0; qf<2; qf++) { f32x4 zv={0.f,0.f,0.f,0.f}; o[d][qf]=zv; }
    float mrun[2] = {-1e30f, -1e30f};
    float lrun[2] = {0.f, 0.f};

    const int nt = 2*(qt+1);
    const float C = 0.125f;

    for (int t = 0; t < nt; ++t) {
        const int kv0 = t*64;
        __syncthreads();
#pragma unroll
        for (int u=0; u<2; ++u) {
            int c = u*256 + tid;
            int row = c >> 3, lc = (c & 7) ^ (row & 7);
            gload16(&qkvf[((long)b*S + kv0 + row)*3072 + 1024 + hd*64 + lc*8], &Kl[c*8]);
        }
#pragma unroll
        for (int u=0; u<2; ++u) {
            int c = u*256 + tid;
            int row = c >> 3, lc = (c & 7) ^ (row & 7);
            gload16(&vtg[((long)bh*DH + row)*S + kv0 + lc*8], &Vtl[c*8]);
        }
        __syncthreads();

        f32x4 s[4][2];
#pragma unroll
        for (int f=0; f<4; f++)
#pragma unroll
            for (int qf=0; qf<2; qf++) { f32x4 zv={0.f,0.f,0.f,0.f}; s[f][qf]=zv; }
        __builtin_amdgcn_s_setprio(1);
#pragma unroll
        for (int f=0; f<4; f++) {
            int krow = f*16 + l16;
#pragma unroll
            for (int dhh=0; dhh<2; dhh++) {
                bf16x8 kfr = *(const bf16x8*)&Kl[krow*64 + (((dhh*4+lh) ^ (krow&7))*8)];
#pragma unroll
                for (int qf=0; qf<2; qf++)
                    s[f][qf] = __builtin_amdgcn_mfma_f32_16x16x32_bf16(kfr, qr[qf][dhh], s[f][qf], 0,0,0);
            }
        }
        __builtin_amdgcn_s_setprio(0);

        const bool needmask = (kv0 + 64 > wq_lo);

#pragma unroll
        for (int qf=0; qf<2; qf++) {
            int qg = wq_lo + qf*16 + l16;
            float pmax = -1e30f;
#pragma unroll
            for (int f=0; f<4; f++)
#pragma unroll
                for (int r=0; r<4; r++) {
                    float sv = s[f][qf][r];
                    if (needmask && (kv0 + f*16 + lh*4 + r > qg)) { sv = -1e30f; s[f][qf][r] = sv; }
                    pmax = fmaxf(pmax, sv);
                }
            pmax = fmaxf(pmax, __shfl_xor(pmax, 16));
            pmax = fmaxf(pmax, __shfl_xor(pmax, 32));
            float mnew = fmaxf(mrun[qf], pmax);
            float corr = __expf((mrun[qf] - mnew)*C);
            mrun[qf] = mnew;
            lrun[qf] *= corr;
#pragma unroll
            for (int d=0; d<4; d++) o[d][qf] *= corr;
            float lsum = 0.f;
            int qloc = qf*16 + l16;
#pragma unroll
            for (int f=0; f<4; f++) {
                ushort4 pk;
                float p0 = __expf((s[f][qf][0]-mnew)*C);
                float p1 = __expf((s[f][qf][1]-mnew)*C);
                float p2 = __expf((s[f][qf][2]-mnew)*C);
                float p3 = __expf((s[f][qf][3]-mnew)*C);
                lsum += (p0+p1) + (p2+p3);
                pk.x = bfbits(p0); pk.y = bfbits(p1); pk.z = bfbits(p2); pk.w = bfbits(p3);
                int phys = (f*2 + (lh>>1)) ^ (qloc & 7);
                *(ushort4*)&Pw[qloc*64 + phys*8 + (lh&1)*4] = pk;
            }
            lrun[qf] += lsum;
        }

#pragma unroll
        for (int kh=0; kh<2; kh++) {
            bf16x8 pb[2];
#pragma unroll
            for (int qf=0; qf<2; qf++) {
                int qloc = qf*16 + l16;
                pb[qf] = *(const bf16x8*)&Pw[qloc*64 + (((kh*4+lh) ^ (qloc&7))*8)];
            }
            __builtin_amdgcn_s_setprio(1);
#pragma unroll
            for (int d=0; d<4; d++) {
                int vrow = d*16 + l16;
                bf16x8 va = *(const bf16x8*)&Vtl[vrow*64 + (((kh*4+lh) ^ (vrow&7))*8)];
#pragma unroll
                for (int qf=0; qf<2; qf++)
                    o[d][qf] = __builtin_amdgcn_mfma_f32_16x16x32_bf16(va, pb[qf], o[d][qf], 0,0,0);
            }
            __builtin_amdgcn_s_setprio(0);
        }
    }

#pragma unroll
    for (int qf=0; qf<2; qf++) {
        float lt = lrun[qf];
        lt += __shfl_xor(lt, 16);
        lt += __shfl_xor(lt, 32);
        float inv = 1.0f / lt;
        int qg = wq_lo + qf*16 + l16;
#pragma unroll
        for (int d=0; d<4; d++) {
            ushort4 ov;
            ov.x = bfbits(o[d][qf][0]*inv);
            ov.y = bfbits(o[d][qf][1]*inv);
            ov.z = bfbits(o[d][qf][2]*inv);
            ov.w = bfbits(o[d][qf][3]*inv);
            *(ushort4*)&zf[((long)b*S + qg)*DM + hd*64 + d*16 + lh*4] = ov;
        }
    }
}

// ---------------------------------------------------------------------------
// Weight conversion kernels (vectorized: float4 read, ushort4 write)
// ---------------------------------------------------------------------------
__global__ __launch_bounds__(256) void k_conv_qkv(
    const float* __restrict__ Wq, const float* __restrict__ Wk,
    const float* __restrict__ Wv, bf16_t* __restrict__ out)
{
    long idx = ((long)blockIdx.x*256 + threadIdx.x)*4;   // NL*3072*DM total
    long l = idx / (3072L*DM);
    long r = idx % (3072L*DM);
    int row = (int)(r / DM), d = (int)(r % DM);
    int sel = row >> 10, rr = row & 1023;
    const float* src = sel==0 ? Wq : (sel==1 ? Wk : Wv);
    float4 v = *(const float4*)&src[(l*1024 + rr)*(long)DM + d];
    ushort4 o;
    o.x = bfbits(v.x); o.y = bfbits(v.y); o.z = bfbits(v.z); o.w = bfbits(v.w);
    *(ushort4*)&out[idx] = o;
}

__global__ __launch_bounds__(256) void k_conv(const float* __restrict__ src,
                                              bf16_t* __restrict__ dst, long n)
{
    long i = ((long)blockIdx.x*256 + threadIdx.x)*4;
    if (i >= n) return;
    float4 v = *(const float4*)&src[i];
    ushort4 o;
    o.x = bfbits(v.x); o.y = bfbits(v.y); o.z = bfbits(v.z); o.w = bfbits(v.w);
    *(ushort4*)&dst[i] = o;
}

// W [DM][NC] f32 -> out [NC][DM] bf16 (tiled transpose; W_U and W_E)
__global__ __launch_bounds__(256) void k_trans(const float* __restrict__ W,
                                               bf16_t* __restrict__ out, int NC)
{
    __shared__ float tile[32][33];
    int n0 = blockIdx.x*32, k0 = blockIdx.y*32;
    int tx = threadIdx.x & 31, ty = threadIdx.x >> 5;
#pragma unroll
    for (int u=0;u<4;u++)
        tile[ty+u*8][tx] = W[(long)(k0+ty+u*8)*NC + n0+tx];
    __syncthreads();
#pragma unroll
    for (int u=0;u<4;u++)
        out[(long)(n0+ty+u*8)*DM + k0+tx] = (bf16_t)tile[tx][ty+u*8];
}

// ---------------------------------------------------------------------------
// Embedding from TRANSPOSED W_E: x[b,p,:] = WEt[tok[b,p],:] + W_pos[p,:]
// ---------------------------------------------------------------------------
__global__ __launch_bounds__(256) void k_embed(const int* __restrict__ tok,
    const bf16_t* __restrict__ WEt, const float* __restrict__ Wpos,
    float* __restrict__ xf, bf16_t* __restrict__ xb)
{
    int bp = blockIdx.x;
    int p  = bp & (S-1);
    int t  = tok[bp];
    int d  = threadIdx.x*4;
    ushort4 e = *(const ushort4*)&WEt[(long)t*DM + d];
    float4  w = *(const float4*)&Wpos[(long)p*DM + d];
    float4 v;
    v.x = b2f(e.x)+w.x; v.y = b2f(e.y)+w.y; v.z = b2f(e.z)+w.z; v.w = b2f(e.w)+w.w;
    *(float4*)&xf[(long)bp*DM + d] = v;
    ushort4 o;
    o.x = bfbits(v.x); o.y = bfbits(v.y); o.z = bfbits(v.z); o.w = bfbits(v.w);
    *(ushort4*)&xb[(long)bp*DM + d] = o;
}

// qkv_flat V-part -> vT[b,h,dh,p], LDS-tiled transpose
__global__ __launch_bounds__(256) void k_permv(const bf16_t* __restrict__ qkv,
    bf16_t* __restrict__ vt)
{
    __shared__ bf16_t tile[64][66];
    const int p0 = blockIdx.x*64;
    const int bh = blockIdx.y;
    const int b  = bh >> 4, hd = bh & 15;
    const int tx = threadIdx.x & 63, ty = threadIdx.x >> 6;
#pragma unroll
    for (int u=0;u<16;u++) {
        int r = u*4 + ty;
        tile[r][tx] = qkv[((long)b*S + p0 + r)*3072 + 2048 + hd*64 + tx];
    }
    __syncthreads();
#pragma unroll
    for (int u=0;u<16;u++) {
        int hh = u*4 + ty;
        vt[(((long)bh)*DH + hh)*S + p0 + tx] = tile[tx][hh];
    }
}

// ---------------------------------------------------------------------------
extern "C" void kernel_launch(void* const* d_in, const int* in_sizes, int n_in,
                              void* d_out, int out_size, void* d_ws, size_t ws_size,
                              hipStream_t stream)
{
    const int*   tokens = (const int*)d_in[0];
    const float* W_E    = (const float*)d_in[1];
    const float* W_pos  = (const float*)d_in[2];
    const float* W_K    = (const float*)d_in[3];
    const float* W_Q    = (const float*)d_in[4];
    const float* W_V    = (const float*)d_in[5];
    const float* W_O    = (const float*)d_in[6];
    const float* W_in   = (const float*)d_in[7];
    const float* b_in   = (const float*)d_in[8];
    const float* W_out  = (const float*)d_in[9];
    const float* b_out  = (const float*)d_in[10];
    const float* W_U    = (const float*)d_in[11];
    float* out = (float*)d_out;

    char* ws = (char*)d_ws;
    long off = 0;
    auto alloc = [&](long bytes)->char* {
        char* p = ws + off; off += (bytes + 255) & ~255L; return p;
    };
    bf16_t* wqkv = (bf16_t*)alloc((long)NL*3072*DM*2);
    bf16_t* wo   = (bf16_t*)alloc((long)NL*DM*DM*2);
    bf16_t* win  = (bf16_t*)alloc((long)NL*DMLP*DM*2);
    bf16_t* wout = (bf16_t*)alloc((long)NL*DM*DMLP*2);
    bf16_t* wut  = (bf16_t*)alloc((long)DV*DM*2);
    bf16_t* wet  = (bf16_t*)alloc((long)DV*DM*2);
    float*  xf   = (float*)alloc((long)MTOK*DM*4);
    bf16_t* xb   = (bf16_t*)alloc((long)MTOK*DM*2);
    bf16_t* qkvf = (bf16_t*)alloc((long)MTOK*3072*2);
    bf16_t* vt   = (bf16_t*)alloc((long)BATCH*NH*S*DH*2);
    bf16_t* zf   = (bf16_t*)alloc((long)MTOK*DM*2);
    bf16_t* post = (bf16_t*)alloc((long)MTOK*DMLP*2);

    // --- weight conversion (per launch; deterministic) ---
    k_conv_qkv<<<(int)(((long)NL*3072*DM)/1024), 256, 0, stream>>>(W_Q, W_K, W_V, wqkv);
    k_conv<<<(int)(((long)NL*DM*DM)/1024),   256, 0, stream>>>(W_O,   wo,   (long)NL*DM*DM);
    k_conv<<<(int)(((long)NL*DMLP*DM)/1024), 256, 0, stream>>>(W_in,  win,  (long)NL*DMLP*DM);
    k_conv<<<(int)(((long)NL*DM*DMLP)/1024), 256, 0, stream>>>(W_out, wout, (long)NL*DM*DMLP);
    k_trans<<<dim3(DV/32, DM/32), 256, 0, stream>>>(W_U, wut, DV);
    k_trans<<<dim3(DV/32, DM/32), 256, 0, stream>>>(W_E, wet, DV);

    // --- embed ---
    k_embed<<<MTOK, 256, 0, stream>>>(tokens, wet, W_pos, xf, xb);

    for (int l = 0; l < NL; ++l) {
        // QKV (fused N=3072): 128d, grid 32x24=768 blocks, 2/CU
        gemm128d<0,false,false><<<dim3(MTOK/128, 3072/128), 256, 0, stream>>>(
            xb, wqkv + (long)l*3072*DM, (char*)qkvf, 3072, nullptr, nullptr, nullptr, DM);
        k_permv<<<dim3(S/64, BATCH*NH), 256, 0, stream>>>(qkvf, vt);

        // fused causal attention -> z_flat
        flash_attn<<<dim3(S/128, BATCH*NH), 256, 0, stream>>>(qkvf, vt, zf);

        // attn_out = z_flat @ W_O^T, fused residual add into x
        gemm128d<2,false,false><<<dim3(MTOK/128, DM/128), 256, 0, stream>>>(
            zf, wo + (long)l*DM*DM, nullptr, DM, nullptr, xf, xb, DM);
        // MLP in: relu(x @ W_in^T + b_in): 256-tile (grid 16x16 = 256 blocks)
        gemm256<0,true,true><<<dim3(MTOK/256, DMLP/256), 512, 0, stream>>>(
            xb, win + (long)l*DMLP*DM, (char*)post, DMLP,
            b_in + (long)l*DMLP, DM);
        // MLP out + b_out, fused residual add into x
        gemm128d<2,true,false><<<dim3(MTOK/128, DM/128), 256, 0, stream>>>(
            post, wout + (long)l*DM*DMLP, nullptr, DM,
            b_out + (long)l*DM, xf, xb, DMLP);
    }

    // logits = x @ W_U (f32 out, full-line nt stores)
    gemm128d<1,false,false><<<dim3(MTOK/128, DV/128), 256, 0, stream>>>(
        xb, wut, (char*)out, DV, nullptr, nullptr, nullptr, DM);
}

// Round 13
// 1565.244 us; speedup vs baseline: 1.0840x; 1.0157x over previous
//
#include <hip/hip_runtime.h>
#include <hip/hip_bf16.h>
#include <math.h>

// Model dims
#define DV   32000
#define DM   1024
#define DMLP 4096
#define DH   64
#define NH   16
#define NL   4
#define BATCH 2
#define S    2048
#define MTOK (BATCH*S)   // 4096 tokens

typedef __bf16 bf16_t;
typedef bf16_t bf16x8 __attribute__((ext_vector_type(8)));
typedef float  f32x4  __attribute__((ext_vector_type(4)));

#define AS1 __attribute__((address_space(1)))
#define AS3 __attribute__((address_space(3)))

__device__ __forceinline__ void gload16(const bf16_t* g, bf16_t* l) {
    __builtin_amdgcn_global_load_lds((const AS1 void*)g, (AS3 void*)l, 16, 0, 0);
}

__device__ __forceinline__ unsigned short bfbits(float v) {
    union { bf16_t b; unsigned short u; } c; c.b = (bf16_t)v; return c.u;
}
__device__ __forceinline__ float b2f(unsigned short u) {
    union { float f; unsigned v; } c; c.v = ((unsigned)u) << 16; return c.f;
}

// ---------------------------------------------------------------------------
// 128x128 double-buffered counted-vmcnt TN GEMM. 256 threads = 4 waves
// (2Mx2N), per-wave 64x64. Used for K=1024/4096 mid-shapes (measured round
// 12: better than gemm256 there; worse for the 32000-wide unembed).
// MODE 0: bf16 out (+bias/relu). MODE 1: f32 out (LDS-transposed nt).
// MODE 2: resid_f32 += acc(+bias); residb=bf16.
// ---------------------------------------------------------------------------
template<int MODE, bool BIAS, bool RELU>
__global__ __launch_bounds__(256, 2)
void gemm128d(const bf16_t* __restrict__ A, const bf16_t* __restrict__ Bm,
              char* __restrict__ Out, int ldc,
              const float* __restrict__ bias,
              float* __restrict__ resid, bf16_t* __restrict__ residb,
              int K)
{
    const int mb = blockIdx.x, nb = blockIdx.y;

    __shared__ alignas(16) bf16_t lds[2][2][128*64];

    const int tid  = threadIdx.x;
    const int wave = tid >> 6, lane = tid & 63;
    const int wm = wave >> 1, wn = wave & 1;
    const int l16 = lane & 15, lh = lane >> 4;

    const bf16_t* Abase = A  + (long)(mb*128)*K;
    const bf16_t* Bbase = Bm + (long)(nb*128)*K;

    auto stage = [&](int buf, int mat, int k0) {
        const bf16_t* src = (mat ? Bbase : Abase) + k0;
        bf16_t* dst = &lds[buf][mat][0];
#pragma unroll
        for (int u=0; u<4; ++u) {
            int c = u*256 + tid;
            int row = c >> 3, lc = (c & 7) ^ (row & 7);
            gload16(&src[(long)row*K + lc*8], dst + c*8);
        }
    };

    f32x4 acc[4][4];
#pragma unroll
    for (int i=0;i<4;i++)
#pragma unroll
        for (int j=0;j<4;j++) { f32x4 zv={0.f,0.f,0.f,0.f}; acc[i][j]=zv; }

    const int NT = K >> 6;
    stage(0,0,0); stage(0,1,0);

    int cur = 0;
    for (int kt = 0; kt < NT; ++kt) {
        const int nxt = cur ^ 1;
        const int k1 = (kt+1) << 6;
        const bool more = (kt+1 < NT);

        if (more) {
            stage(nxt,0,k1);
            asm volatile("s_waitcnt vmcnt(4)" ::: "memory");
        } else {
            asm volatile("s_waitcnt vmcnt(0)" ::: "memory");
        }
        asm volatile("s_barrier" ::: "memory");

        bf16x8 af[4][2], bfr[4][2];
#pragma unroll
        for (int i=0;i<4;i++) {
            int ra = wm*64 + i*16 + l16;
#pragma unroll
            for (int kk=0;kk<2;kk++)
                af[i][kk] = *(const bf16x8*)&lds[cur][0][ra*64 + (((kk*4+lh)^(ra&7))*8)];
        }
#pragma unroll
        for (int j=0;j<2;j++) {
            int rb = wn*64 + j*16 + l16;
#pragma unroll
            for (int kk=0;kk<2;kk++)
                bfr[j][kk] = *(const bf16x8*)&lds[cur][1][rb*64 + (((kk*4+lh)^(rb&7))*8)];
        }
        __builtin_amdgcn_s_setprio(1);
#pragma unroll
        for (int kk=0;kk<2;kk++)
#pragma unroll
            for (int i=0;i<4;i++)
#pragma unroll
                for (int j=0;j<2;j++)
                    acc[i][j] = __builtin_amdgcn_mfma_f32_16x16x32_bf16(af[i][kk], bfr[j][kk], acc[i][j], 0,0,0);
        __builtin_amdgcn_s_setprio(0);

        if (more) stage(nxt,1,k1);
#pragma unroll
        for (int j=2;j<4;j++) {
            int rb = wn*64 + j*16 + l16;
#pragma unroll
            for (int kk=0;kk<2;kk++)
                bfr[j][kk] = *(const bf16x8*)&lds[cur][1][rb*64 + (((kk*4+lh)^(rb&7))*8)];
        }
        __builtin_amdgcn_s_setprio(1);
#pragma unroll
        for (int kk=0;kk<2;kk++)
#pragma unroll
            for (int i=0;i<4;i++)
#pragma unroll
                for (int j=2;j<4;j++)
                    acc[i][j] = __builtin_amdgcn_mfma_f32_16x16x32_bf16(af[i][kk], bfr[j][kk], acc[i][j], 0,0,0);
        __builtin_amdgcn_s_setprio(0);

        asm volatile("s_barrier" ::: "memory");
        cur = nxt;
    }

    if constexpr (MODE == 1) {
        float* lsl = reinterpret_cast<float*>(&lds[0][0][0]) + wave*(32*68);
        const int lrow = lane >> 4;
        const int lcq  = lane & 15;
#pragma unroll
        for (int ch=0; ch<2; ++ch) {
#pragma unroll
            for (int il=0; il<2; ++il)
#pragma unroll
                for (int j=0;j<4;j++)
#pragma unroll
                    for (int r=0;r<4;r++)
                        lsl[(il*16 + lh*4 + r)*68 + j*16 + l16] = acc[ch*2+il][j][r];
#pragma unroll
            for (int u=0; u<8; ++u) {
                int rl = u*4 + lrow;
                f32x4 v = *(const f32x4*)&lsl[rl*68 + lcq*4];
                long row = mb*128 + wm*64 + ch*32 + rl;
                long col = nb*128 + wn*64 + lcq*4;
                __builtin_nontemporal_store(v, (f32x4*)&((float*)Out)[row*ldc + col]);
            }
        }
    } else {
#pragma unroll
        for (int i=0;i<4;i++) {
            int row0 = mb*128 + wm*64 + i*16 + lh*4;
#pragma unroll
            for (int j=0;j<4;j++) {
                int col = nb*128 + wn*64 + j*16 + l16;
                float bv = BIAS ? bias[col] : 0.0f;
#pragma unroll
                for (int r=0;r<4;r++) {
                    int row = row0 + r;
                    float v = acc[i][j][r] + bv;
                    if (RELU) v = v > 0.f ? v : 0.f;
                    if constexpr (MODE == 0) {
                        ((bf16_t*)Out)[(long)row*ldc + col] = (bf16_t)v;
                    } else {
                        long o2 = (long)row*ldc + col;
                        float nv = resid[o2] + v;
                        resid[o2]  = nv;
                        residb[o2] = (bf16_t)nv;
                    }
                }
            }
        }
    }
}

// ---------------------------------------------------------------------------
// 256x256 deep-pipelined TN GEMM — used for the unembed (measured 318 µs
// vs gemm128d's 379: more MFMA per barrier wins at N=32000).
// MODE 0: bf16 out (+bias/relu); MODE 1: f32 out via LDS-transposed
// full-line f32x4 nontemporal stores.
// ---------------------------------------------------------------------------
template<int MODE, bool BIAS, bool RELU>
__global__ __launch_bounds__(512, 1)
void gemm256(const bf16_t* __restrict__ A, const bf16_t* __restrict__ Bm,
             char* __restrict__ Out, int ldc,
             const float* __restrict__ bias, int K)
{
    const int mb = blockIdx.x, nb = blockIdx.y;

    __shared__ alignas(16) bf16_t lds[2][2][2][128*64];

    const int tid  = threadIdx.x;
    const int wave = tid >> 6, lane = tid & 63;
    const int wm = wave >> 2, wn = wave & 3;
    const int l16 = lane & 15, lh = lane >> 4;

    const bf16_t* Abase = A  + (long)(mb*256)*K;
    const bf16_t* Bbase = Bm + (long)(nb*256)*K;

    const int c0 = tid,       r0 = c0 >> 3, lc0 = (c0 & 7) ^ (r0 & 7);
    const int c1 = 512 + tid, r1 = c1 >> 3, lc1 = (c1 & 7) ^ (r1 & 7);

    auto stage = [&](int buf, int mat, int half, int k0) {
        const bf16_t* src = (mat ? Bbase : Abase) + (long)(half*128)*K + k0;
        bf16_t* dst = &lds[buf][mat][half][0];
        gload16(&src[(long)r0*K + lc0*8], dst + c0*8);
        gload16(&src[(long)r1*K + lc1*8], dst + c1*8);
    };

    f32x4 acc[8][4];
#pragma unroll
    for (int i=0;i<8;i++)
#pragma unroll
        for (int j=0;j<4;j++) { f32x4 zv={0.f,0.f,0.f,0.f}; acc[i][j]=zv; }

    const int NT = K >> 6;
    stage(0,0,0,0); stage(0,0,1,0); stage(0,1,0,0); stage(0,1,1,0);

    int cur = 0;
    for (int kt = 0; kt < NT; ++kt) {
        const int nxt = cur ^ 1;
        const int k1 = (kt+1) << 6;
        const bool more = (kt+1 < NT);

        if (more) {
            stage(nxt,0,0,k1);
            asm volatile("s_waitcnt vmcnt(2)" ::: "memory");
        } else {
            asm volatile("s_waitcnt vmcnt(0)" ::: "memory");
        }
        asm volatile("s_barrier" ::: "memory");

        bf16x8 af[4][2], bfr[4][2];
#pragma unroll
        for (int i=0;i<4;i++) {
            int ra = i*16 + l16;
#pragma unroll
            for (int kk=0;kk<2;kk++)
                af[i][kk] = *(const bf16x8*)&lds[cur][0][wm][ra*64 + (((kk*4+lh)^(ra&7))*8)];
        }
#pragma unroll
        for (int j=0;j<2;j++) {
            int rb = (wn&1)*64 + j*16 + l16;
#pragma unroll
            for (int kk=0;kk<2;kk++)
                bfr[j][kk] = *(const bf16x8*)&lds[cur][1][wn>>1][rb*64 + (((kk*4+lh)^(rb&7))*8)];
        }
        __builtin_amdgcn_s_setprio(1);
#pragma unroll
        for (int kk=0;kk<2;kk++)
#pragma unroll
            for (int i=0;i<4;i++)
#pragma unroll
                for (int j=0;j<2;j++)
                    acc[i][j] = __builtin_amdgcn_mfma_f32_16x16x32_bf16(af[i][kk], bfr[j][kk], acc[i][j], 0,0,0);
        __builtin_amdgcn_s_setprio(0);

        if (more) stage(nxt,0,1,k1);
#pragma unroll
        for (int j=2;j<4;j++) {
            int rb = (wn&1)*64 + j*16 + l16;
#pragma unroll
            for (int kk=0;kk<2;kk++)
                bfr[j][kk] = *(const bf16x8*)&lds[cur][1][wn>>1][rb*64 + (((kk*4+lh)^(rb&7))*8)];
        }
        __builtin_amdgcn_s_setprio(1);
#pragma unroll
        for (int kk=0;kk<2;kk++)
#pragma unroll
            for (int i=0;i<4;i++)
#pragma unroll
                for (int j=2;j<4;j++)
                    acc[i][j] = __builtin_amdgcn_mfma_f32_16x16x32_bf16(af[i][kk], bfr[j][kk], acc[i][j], 0,0,0);
        __builtin_amdgcn_s_setprio(0);

        if (more) stage(nxt,1,0,k1);
#pragma unroll
        for (int i=0;i<4;i++) {
            int ra = (i+4)*16 + l16;
#pragma unroll
            for (int kk=0;kk<2;kk++)
                af[i][kk] = *(const bf16x8*)&lds[cur][0][wm][ra*64 + (((kk*4+lh)^(ra&7))*8)];
        }
        __builtin_amdgcn_s_setprio(1);
#pragma unroll
        for (int kk=0;kk<2;kk++)
#pragma unroll
            for (int i=0;i<4;i++)
#pragma unroll
                for (int j=0;j<2;j++)
                    acc[i+4][j] = __builtin_amdgcn_mfma_f32_16x16x32_bf16(af[i][kk], bfr[j][kk], acc[i+4][j], 0,0,0);
        __builtin_amdgcn_s_setprio(0);

        if (more) stage(nxt,1,1,k1);
        __builtin_amdgcn_s_setprio(1);
#pragma unroll
        for (int kk=0;kk<2;kk++)
#pragma unroll
            for (int i=0;i<4;i++)
#pragma unroll
                for (int j=2;j<4;j++)
                    acc[i+4][j] = __builtin_amdgcn_mfma_f32_16x16x32_bf16(af[i][kk], bfr[j][kk], acc[i+4][j], 0,0,0);
        __builtin_amdgcn_s_setprio(0);

        asm volatile("s_barrier" ::: "memory");
        cur = nxt;
    }

    if constexpr (MODE == 1) {
        float* lsl = reinterpret_cast<float*>(&lds[0][0][0][0]) + wave*(32*68);
        const int lrow = lane >> 4;
        const int lcq  = lane & 15;
#pragma unroll
        for (int ch=0; ch<4; ++ch) {
#pragma unroll
            for (int il=0; il<2; ++il)
#pragma unroll
                for (int j=0;j<4;j++)
#pragma unroll
                    for (int r=0;r<4;r++)
                        lsl[(il*16 + lh*4 + r)*68 + j*16 + l16] = acc[ch*2+il][j][r];
#pragma unroll
            for (int u=0; u<8; ++u) {
                int rl = u*4 + lrow;
                f32x4 v = *(const f32x4*)&lsl[rl*68 + lcq*4];
                long row = mb*256 + wm*128 + ch*32 + rl;
                long col = nb*256 + wn*64 + lcq*4;
                __builtin_nontemporal_store(v, (f32x4*)&((float*)Out)[row*ldc + col]);
            }
        }
    } else {
#pragma unroll
        for (int i=0;i<8;i++) {
            int row0 = mb*256 + wm*128 + i*16 + lh*4;
#pragma unroll
            for (int j=0;j<4;j++) {
                int col = nb*256 + wn*64 + j*16 + l16;
                float bv = BIAS ? bias[col] : 0.0f;
#pragma unroll
                for (int r=0;r<4;r++) {
                    int row = row0 + r;
                    float v = acc[i][j][r] + bv;
                    if (RELU) v = v > 0.f ? v : 0.f;
                    ((bf16_t*)Out)[(long)row*ldc + col] = (bf16_t)v;
                }
            }
        }
    }
}

// ---------------------------------------------------------------------------
// Flash attention (causal), KV double-buffered with counted vmcnt.
// Grid: (S/128, BATCH*NH), 4 waves/block, LDS 48 KiB -> 2 blocks/CU.
// Per tile: issue next-tile K+V stage (4 loads/thread) AFTER the end
// barrier of the previous tile, wait vmcnt(4) (current tile landed, next
// stays in flight), compute QK^T/softmax/PV, end barrier.
// ---------------------------------------------------------------------------
__global__ __launch_bounds__(256)
void flash_attn(const bf16_t* __restrict__ qkvf,  // [B][S][3072]
                const bf16_t* __restrict__ vtg,   // [BH][DH][S]
                bf16_t* __restrict__ zf)          // [B][S][DM]
{
    const int qt = blockIdx.x;
    const int bh = blockIdx.y;
    const int b  = bh >> 4, hd = bh & 15;

    __shared__ alignas(16) bf16_t Kl[2][64*64];
    __shared__ alignas(16) bf16_t Vtl[2][64*64];
    __shared__ alignas(16) bf16_t Pl[4*32*64];

    const int tid = threadIdx.x;
    const int wave = tid >> 6, lane = tid & 63;
    const int l16 = lane & 15, lh = lane >> 4;
    const int wq_lo = qt*128 + wave*32;
    bf16_t* Pw = Pl + wave*32*64;

    auto stageKV = [&](int buf, int kv0) {
#pragma unroll
        for (int u=0; u<2; ++u) {
            int c = u*256 + tid;
            int row = c >> 3, lc = (c & 7) ^ (row & 7);
            gload16(&qkvf[((long)b*S + kv0 + row)*3072 + 1024 + hd*64 + lc*8], &Kl[buf][c*8]);
        }
#pragma unroll
        for (int u=0; u<2; ++u) {
            int c = u*256 + tid;
            int row = c >> 3, lc = (c & 7) ^ (row & 7);
            gload16(&vtg[((long)bh*DH + row)*S + kv0 + lc*8], &Vtl[buf][c*8]);
        }
    };

    bf16x8 qr[2][2];
#pragma unroll
    for (int qf=0; qf<2; qf++) {
        int qg = wq_lo + qf*16 + l16;
#pragma unroll
        for (int dhh=0; dhh<2; dhh++)
            qr[qf][dhh] = *(const bf16x8*)&qkvf[((long)b*S + qg)*3072 + hd*64 + dhh*32 + lh*8];
    }

    f32x4 o[4][2];
#pragma unroll
    for (int d=0; d<4; d++)
#pragma unroll
        for (int qf=0; qf<2; qf++) { f32x4 zv={0.f,0.f,0.f,0.f}; o[d][qf]=zv; }
    float mrun[2] = {-1e30f, -1e30f};
    float lrun[2] = {0.f, 0.f};

    const int nt = 2*(qt+1);
    const float C = 0.125f;

    stageKV(0, 0);
    int cur = 0;
    for (int t = 0; t < nt; ++t) {
        const int nxt = cur ^ 1;
        const bool more = (t+1 < nt);
        if (more) {
            stageKV(nxt, (t+1)*64);
            asm volatile("s_waitcnt vmcnt(4)" ::: "memory");
        } else {
            asm volatile("s_waitcnt vmcnt(0)" ::: "memory");
        }
        asm volatile("s_barrier" ::: "memory");

        const int kv0 = t*64;
        f32x4 s[4][2];
#pragma unroll
        for (int f=0; f<4; f++)
#pragma unroll
            for (int qf=0; qf<2; qf++) { f32x4 zv={0.f,0.f,0.f,0.f}; s[f][qf]=zv; }
        __builtin_amdgcn_s_setprio(1);
#pragma unroll
        for (int f=0; f<4; f++) {
            int krow = f*16 + l16;
#pragma unroll
            for (int dhh=0; dhh<2; dhh++) {
                bf16x8 kfr = *(const bf16x8*)&Kl[cur][krow*64 + (((dhh*4+lh) ^ (krow&7))*8)];
#pragma unroll
                for (int qf=0; qf<2; qf++)
                    s[f][qf] = __builtin_amdgcn_mfma_f32_16x16x32_bf16(kfr, qr[qf][dhh], s[f][qf], 0,0,0);
            }
        }
        __builtin_amdgcn_s_setprio(0);

        const bool needmask = (kv0 + 64 > wq_lo);

#pragma unroll
        for (int qf=0; qf<2; qf++) {
            int qg = wq_lo + qf*16 + l16;
            float pmax = -1e30f;
#pragma unroll
            for (int f=0; f<4; f++)
#pragma unroll
                for (int r=0; r<4; r++) {
                    float sv = s[f][qf][r];
                    if (needmask && (kv0 + f*16 + lh*4 + r > qg)) { sv = -1e30f; s[f][qf][r] = sv; }
                    pmax = fmaxf(pmax, sv);
                }
            pmax = fmaxf(pmax, __shfl_xor(pmax, 16));
            pmax = fmaxf(pmax, __shfl_xor(pmax, 32));
            float mnew = fmaxf(mrun[qf], pmax);
            float corr = __expf((mrun[qf] - mnew)*C);
            mrun[qf] = mnew;
            lrun[qf] *= corr;
#pragma unroll
            for (int d=0; d<4; d++) o[d][qf] *= corr;
            float lsum = 0.f;
            int qloc = qf*16 + l16;
#pragma unroll
            for (int f=0; f<4; f++) {
                ushort4 pk;
                float p0 = __expf((s[f][qf][0]-mnew)*C);
                float p1 = __expf((s[f][qf][1]-mnew)*C);
                float p2 = __expf((s[f][qf][2]-mnew)*C);
                float p3 = __expf((s[f][qf][3]-mnew)*C);
                lsum += (p0+p1) + (p2+p3);
                pk.x = bfbits(p0); pk.y = bfbits(p1); pk.z = bfbits(p2); pk.w = bfbits(p3);
                int phys = (f*2 + (lh>>1)) ^ (qloc & 7);
                *(ushort4*)&Pw[qloc*64 + phys*8 + (lh&1)*4] = pk;
            }
            lrun[qf] += lsum;
        }

#pragma unroll
        for (int kh=0; kh<2; kh++) {
            bf16x8 pb[2];
#pragma unroll
            for (int qf=0; qf<2; qf++) {
                int qloc = qf*16 + l16;
                pb[qf] = *(const bf16x8*)&Pw[qloc*64 + (((kh*4+lh) ^ (qloc&7))*8)];
            }
            __builtin_amdgcn_s_setprio(1);
#pragma unroll
            for (int d=0; d<4; d++) {
                int vrow = d*16 + l16;
                bf16x8 va = *(const bf16x8*)&Vtl[cur][vrow*64 + (((kh*4+lh) ^ (vrow&7))*8)];
#pragma unroll
                for (int qf=0; qf<2; qf++)
                    o[d][qf] = __builtin_amdgcn_mfma_f32_16x16x32_bf16(va, pb[qf], o[d][qf], 0,0,0);
            }
            __builtin_amdgcn_s_setprio(0);
        }
        asm volatile("s_barrier" ::: "memory");   // all waves done with buf cur
        cur = nxt;
    }

#pragma unroll
    for (int qf=0; qf<2; qf++) {
        float lt = lrun[qf];
        lt += __shfl_xor(lt, 16);
        lt += __shfl_xor(lt, 32);
        float inv = 1.0f / lt;
        int qg = wq_lo + qf*16 + l16;
#pragma unroll
        for (int d=0; d<4; d++) {
            ushort4 ov;
            ov.x = bfbits(o[d][qf][0]*inv);
            ov.y = bfbits(o[d][qf][1]*inv);
            ov.z = bfbits(o[d][qf][2]*inv);
            ov.w = bfbits(o[d][qf][3]*inv);
            *(ushort4*)&zf[((long)b*S + qg)*DM + hd*64 + d*16 + lh*4] = ov;
        }
    }
}

// ---------------------------------------------------------------------------
// Weight conversion kernels (vectorized)
// ---------------------------------------------------------------------------
__global__ __launch_bounds__(256) void k_conv_qkv(
    const float* __restrict__ Wq, const float* __restrict__ Wk,
    const float* __restrict__ Wv, bf16_t* __restrict__ out)
{
    long idx = ((long)blockIdx.x*256 + threadIdx.x)*4;
    long l = idx / (3072L*DM);
    long r = idx % (3072L*DM);
    int row = (int)(r / DM), d = (int)(r % DM);
    int sel = row >> 10, rr = row & 1023;
    const float* src = sel==0 ? Wq : (sel==1 ? Wk : Wv);
    float4 v = *(const float4*)&src[(l*1024 + rr)*(long)DM + d];
    ushort4 o;
    o.x = bfbits(v.x); o.y = bfbits(v.y); o.z = bfbits(v.z); o.w = bfbits(v.w);
    *(ushort4*)&out[idx] = o;
}

__global__ __launch_bounds__(256) void k_conv(const float* __restrict__ src,
                                              bf16_t* __restrict__ dst, long n)
{
    long i = ((long)blockIdx.x*256 + threadIdx.x)*4;
    if (i >= n) return;
    float4 v = *(const float4*)&src[i];
    ushort4 o;
    o.x = bfbits(v.x); o.y = bfbits(v.y); o.z = bfbits(v.z); o.w = bfbits(v.w);
    *(ushort4*)&dst[i] = o;
}

// W [DM][NC] f32 -> out [NC][DM] bf16 (tiled transpose; W_U and W_E)
__global__ __launch_bounds__(256) void k_trans(const float* __restrict__ W,
                                               bf16_t* __restrict__ out, int NC)
{
    __shared__ float tile[32][33];
    int n0 = blockIdx.x*32, k0 = blockIdx.y*32;
    int tx = threadIdx.x & 31, ty = threadIdx.x >> 5;
#pragma unroll
    for (int u=0;u<4;u++)
        tile[ty+u*8][tx] = W[(long)(k0+ty+u*8)*NC + n0+tx];
    __syncthreads();
#pragma unroll
    for (int u=0;u<4;u++)
        out[(long)(n0+ty+u*8)*DM + k0+tx] = (bf16_t)tile[tx][ty+u*8];
}

// ---------------------------------------------------------------------------
// Embedding from TRANSPOSED W_E
// ---------------------------------------------------------------------------
__global__ __launch_bounds__(256) void k_embed(const int* __restrict__ tok,
    const bf16_t* __restrict__ WEt, const float* __restrict__ Wpos,
    float* __restrict__ xf, bf16_t* __restrict__ xb)
{
    int bp = blockIdx.x;
    int p  = bp & (S-1);
    int t  = tok[bp];
    int d  = threadIdx.x*4;
    ushort4 e = *(const ushort4*)&WEt[(long)t*DM + d];
    float4  w = *(const float4*)&Wpos[(long)p*DM + d];
    float4 v;
    v.x = b2f(e.x)+w.x; v.y = b2f(e.y)+w.y; v.z = b2f(e.z)+w.z; v.w = b2f(e.w)+w.w;
    *(float4*)&xf[(long)bp*DM + d] = v;
    ushort4 o;
    o.x = bfbits(v.x); o.y = bfbits(v.y); o.z = bfbits(v.z); o.w = bfbits(v.w);
    *(ushort4*)&xb[(long)bp*DM + d] = o;
}

// qkv_flat V-part -> vT[b,h,dh,p], LDS-tiled transpose
__global__ __launch_bounds__(256) void k_permv(const bf16_t* __restrict__ qkv,
    bf16_t* __restrict__ vt)
{
    __shared__ bf16_t tile[64][66];
    const int p0 = blockIdx.x*64;
    const int bh = blockIdx.y;
    const int b  = bh >> 4, hd = bh & 15;
    const int tx = threadIdx.x & 63, ty = threadIdx.x >> 6;
#pragma unroll
    for (int u=0;u<16;u++) {
        int r = u*4 + ty;
        tile[r][tx] = qkv[((long)b*S + p0 + r)*3072 + 2048 + hd*64 + tx];
    }
    __syncthreads();
#pragma unroll
    for (int u=0;u<16;u++) {
        int hh = u*4 + ty;
        vt[(((long)bh)*DH + hh)*S + p0 + tx] = tile[tx][hh];
    }
}

// ---------------------------------------------------------------------------
extern "C" void kernel_launch(void* const* d_in, const int* in_sizes, int n_in,
                              void* d_out, int out_size, void* d_ws, size_t ws_size,
                              hipStream_t stream)
{
    const int*   tokens = (const int*)d_in[0];
    const float* W_E    = (const float*)d_in[1];
    const float* W_pos  = (const float*)d_in[2];
    const float* W_K    = (const float*)d_in[3];
    const float* W_Q    = (const float*)d_in[4];
    const float* W_V    = (const float*)d_in[5];
    const float* W_O    = (const float*)d_in[6];
    const float* W_in   = (const float*)d_in[7];
    const float* b_in   = (const float*)d_in[8];
    const float* W_out  = (const float*)d_in[9];
    const float* b_out  = (const float*)d_in[10];
    const float* W_U    = (const float*)d_in[11];
    float* out = (float*)d_out;

    char* ws = (char*)d_ws;
    long off = 0;
    auto alloc = [&](long bytes)->char* {
        char* p = ws + off; off += (bytes + 255) & ~255L; return p;
    };
    bf16_t* wqkv = (bf16_t*)alloc((long)NL*3072*DM*2);
    bf16_t* wo   = (bf16_t*)alloc((long)NL*DM*DM*2);
    bf16_t* win  = (bf16_t*)alloc((long)NL*DMLP*DM*2);
    bf16_t* wout = (bf16_t*)alloc((long)NL*DM*DMLP*2);
    bf16_t* wut  = (bf16_t*)alloc((long)DV*DM*2);
    bf16_t* wet  = (bf16_t*)alloc((long)DV*DM*2);
    float*  xf   = (float*)alloc((long)MTOK*DM*4);
    bf16_t* xb   = (bf16_t*)alloc((long)MTOK*DM*2);
    bf16_t* qkvf = (bf16_t*)alloc((long)MTOK*3072*2);
    bf16_t* vt   = (bf16_t*)alloc((long)BATCH*NH*S*DH*2);
    bf16_t* zf   = (bf16_t*)alloc((long)MTOK*DM*2);
    bf16_t* post = (bf16_t*)alloc((long)MTOK*DMLP*2);

    // --- weight conversion (per launch; deterministic) ---
    k_conv_qkv<<<(int)(((long)NL*3072*DM)/1024), 256, 0, stream>>>(W_Q, W_K, W_V, wqkv);
    k_conv<<<(int)(((long)NL*DM*DM)/1024),   256, 0, stream>>>(W_O,   wo,   (long)NL*DM*DM);
    k_conv<<<(int)(((long)NL*DMLP*DM)/1024), 256, 0, stream>>>(W_in,  win,  (long)NL*DMLP*DM);
    k_conv<<<(int)(((long)NL*DM*DMLP)/1024), 256, 0, stream>>>(W_out, wout, (long)NL*DM*DMLP);
    k_trans<<<dim3(DV/32, DM/32), 256, 0, stream>>>(W_U, wut, DV);
    k_trans<<<dim3(DV/32, DM/32), 256, 0, stream>>>(W_E, wet, DV);

    // --- embed ---
    k_embed<<<MTOK, 256, 0, stream>>>(tokens, wet, W_pos, xf, xb);

    for (int l = 0; l < NL; ++l) {
        // QKV (fused N=3072): 128d
        gemm128d<0,false,false><<<dim3(MTOK/128, 3072/128), 256, 0, stream>>>(
            xb, wqkv + (long)l*3072*DM, (char*)qkvf, 3072, nullptr, nullptr, nullptr, DM);
        k_permv<<<dim3(S/64, BATCH*NH), 256, 0, stream>>>(qkvf, vt);

        // fused causal attention -> z_flat (KV double-buffered)
        flash_attn<<<dim3(S/128, BATCH*NH), 256, 0, stream>>>(qkvf, vt, zf);

        // attn_out = z_flat @ W_O^T, fused residual add into x
        gemm128d<2,false,false><<<dim3(MTOK/128, DM/128), 256, 0, stream>>>(
            zf, wo + (long)l*DM*DM, nullptr, DM, nullptr, xf, xb, DM);
        // MLP in: relu(x @ W_in^T + b_in): 128d (1024 blocks, 2/CU)
        gemm128d<0,true,true><<<dim3(MTOK/128, DMLP/128), 256, 0, stream>>>(
            xb, win + (long)l*DMLP*DM, (char*)post, DMLP,
            b_in + (long)l*DMLP, nullptr, nullptr, DM);
        // MLP out + b_out, fused residual add into x
        gemm128d<2,true,false><<<dim3(MTOK/128, DM/128), 256, 0, stream>>>(
            post, wout + (long)l*DM*DMLP, nullptr, DM,
            b_out + (long)l*DM, xf, xb, DMLP);
    }

    // logits = x @ W_U (f32 out, full-line nt stores): 256-tile
    gemm256<1,false,false><<<dim3(MTOK/256, DV/256), 512, 0, stream>>>(
        xb, wut, (char*)out, DV, nullptr, DM);
}

// Round 14
// 1450.010 us; speedup vs baseline: 1.1702x; 1.0795x over previous
//
#include <hip/hip_runtime.h>
#include <hip/hip_bf16.h>
#include <math.h>

// Model dims
#define DV   32000
#define DM   1024
#define DMLP 4096
#define DH   64
#define NH   16
#define NL   4
#define BATCH 2
#define S    2048
#define MTOK (BATCH*S)   // 4096 tokens

typedef __bf16 bf16_t;
typedef bf16_t bf16x8 __attribute__((ext_vector_type(8)));
typedef float  f32x4  __attribute__((ext_vector_type(4)));

#define AS1 __attribute__((address_space(1)))
#define AS3 __attribute__((address_space(3)))

__device__ __forceinline__ void gload16(const bf16_t* g, bf16_t* l) {
    __builtin_amdgcn_global_load_lds((const AS1 void*)g, (AS3 void*)l, 16, 0, 0);
}

__device__ __forceinline__ unsigned short bfbits(float v) {
    union { bf16_t b; unsigned short u; } c; c.b = (bf16_t)v; return c.u;
}
__device__ __forceinline__ float b2f(unsigned short u) {
    union { float f; unsigned v; } c; c.v = ((unsigned)u) << 16; return c.f;
}

// ---------------------------------------------------------------------------
// 128x128 double-buffered TN GEMM, full-tile-ahead prefetch.
// Round-14 change: ALL next-tile stages issue at the TOP of the iteration;
// vmcnt(8) waits for the PREVIOUS tile's 8 loads (full-tile prefetch
// distance ~500 cyc) while the next tile's 8 stay in flight. (Round 13:
// B staged in phase 1 had only ~16-MFMA distance -> per-tile latency stall.)
// MODE 0: bf16 out (+bias/relu). MODE 1: f32 out (LDS-transposed nt).
// MODE 2: resid_f32 += acc(+bias); residb=bf16.
// ---------------------------------------------------------------------------
template<int MODE, bool BIAS, bool RELU>
__global__ __launch_bounds__(256, 2)
void gemm128d(const bf16_t* __restrict__ A, const bf16_t* __restrict__ Bm,
              char* __restrict__ Out, int ldc,
              const float* __restrict__ bias,
              float* __restrict__ resid, bf16_t* __restrict__ residb,
              int K)
{
    const int mb = blockIdx.x, nb = blockIdx.y;

    __shared__ alignas(16) bf16_t lds[2][2][128*64];

    const int tid  = threadIdx.x;
    const int wave = tid >> 6, lane = tid & 63;
    const int wm = wave >> 1, wn = wave & 1;
    const int l16 = lane & 15, lh = lane >> 4;

    const bf16_t* Abase = A  + (long)(mb*128)*K;
    const bf16_t* Bbase = Bm + (long)(nb*128)*K;

    auto stage2 = [&](int buf, int k0) {     // A + B tile: 8 loads/thread
#pragma unroll
        for (int mat=0; mat<2; ++mat) {
            const bf16_t* src = (mat ? Bbase : Abase) + k0;
            bf16_t* dst = &lds[buf][mat][0];
#pragma unroll
            for (int u=0; u<4; ++u) {
                int c = u*256 + tid;
                int row = c >> 3, lc = (c & 7) ^ (row & 7);
                gload16(&src[(long)row*K + lc*8], dst + c*8);
            }
        }
    };

    f32x4 acc[4][4];
#pragma unroll
    for (int i=0;i<4;i++)
#pragma unroll
        for (int j=0;j<4;j++) { f32x4 zv={0.f,0.f,0.f,0.f}; acc[i][j]=zv; }

    const int NT = K >> 6;
    stage2(0, 0);

    int cur = 0;
    for (int kt = 0; kt < NT; ++kt) {
        const int nxt = cur ^ 1;
        const bool more = (kt+1 < NT);

        if (more) {
            stage2(nxt, (kt+1) << 6);
            asm volatile("s_waitcnt vmcnt(8)" ::: "memory");
        } else {
            asm volatile("s_waitcnt vmcnt(0)" ::: "memory");
        }
        asm volatile("s_barrier" ::: "memory");

        bf16x8 af[4][2], bfr[4][2];
#pragma unroll
        for (int i=0;i<4;i++) {
            int ra = wm*64 + i*16 + l16;
#pragma unroll
            for (int kk=0;kk<2;kk++)
                af[i][kk] = *(const bf16x8*)&lds[cur][0][ra*64 + (((kk*4+lh)^(ra&7))*8)];
        }
#pragma unroll
        for (int j=0;j<2;j++) {
            int rb = wn*64 + j*16 + l16;
#pragma unroll
            for (int kk=0;kk<2;kk++)
                bfr[j][kk] = *(const bf16x8*)&lds[cur][1][rb*64 + (((kk*4+lh)^(rb&7))*8)];
        }
        __builtin_amdgcn_s_setprio(1);
#pragma unroll
        for (int kk=0;kk<2;kk++)
#pragma unroll
            for (int i=0;i<4;i++)
#pragma unroll
                for (int j=0;j<2;j++)
                    acc[i][j] = __builtin_amdgcn_mfma_f32_16x16x32_bf16(af[i][kk], bfr[j][kk], acc[i][j], 0,0,0);
        __builtin_amdgcn_s_setprio(0);

#pragma unroll
        for (int j=2;j<4;j++) {
            int rb = wn*64 + j*16 + l16;
#pragma unroll
            for (int kk=0;kk<2;kk++)
                bfr[j][kk] = *(const bf16x8*)&lds[cur][1][rb*64 + (((kk*4+lh)^(rb&7))*8)];
        }
        __builtin_amdgcn_s_setprio(1);
#pragma unroll
        for (int kk=0;kk<2;kk++)
#pragma unroll
            for (int i=0;i<4;i++)
#pragma unroll
                for (int j=2;j<4;j++)
                    acc[i][j] = __builtin_amdgcn_mfma_f32_16x16x32_bf16(af[i][kk], bfr[j][kk], acc[i][j], 0,0,0);
        __builtin_amdgcn_s_setprio(0);

        asm volatile("s_barrier" ::: "memory");
        cur = nxt;
    }

    if constexpr (MODE == 1) {
        float* lsl = reinterpret_cast<float*>(&lds[0][0][0]) + wave*(32*68);
        const int lrow = lane >> 4;
        const int lcq  = lane & 15;
#pragma unroll
        for (int ch=0; ch<2; ++ch) {
#pragma unroll
            for (int il=0; il<2; ++il)
#pragma unroll
                for (int j=0;j<4;j++)
#pragma unroll
                    for (int r=0;r<4;r++)
                        lsl[(il*16 + lh*4 + r)*68 + j*16 + l16] = acc[ch*2+il][j][r];
#pragma unroll
            for (int u=0; u<8; ++u) {
                int rl = u*4 + lrow;
                f32x4 v = *(const f32x4*)&lsl[rl*68 + lcq*4];
                long row = mb*128 + wm*64 + ch*32 + rl;
                long col = nb*128 + wn*64 + lcq*4;
                __builtin_nontemporal_store(v, (f32x4*)&((float*)Out)[row*ldc + col]);
            }
        }
    } else {
#pragma unroll
        for (int i=0;i<4;i++) {
            int row0 = mb*128 + wm*64 + i*16 + lh*4;
#pragma unroll
            for (int j=0;j<4;j++) {
                int col = nb*128 + wn*64 + j*16 + l16;
                float bv = BIAS ? bias[col] : 0.0f;
#pragma unroll
                for (int r=0;r<4;r++) {
                    int row = row0 + r;
                    float v = acc[i][j][r] + bv;
                    if (RELU) v = v > 0.f ? v : 0.f;
                    if constexpr (MODE == 0) {
                        ((bf16_t*)Out)[(long)row*ldc + col] = (bf16_t)v;
                    } else {
                        long o2 = (long)row*ldc + col;
                        float nv = resid[o2] + v;
                        resid[o2]  = nv;
                        residb[o2] = (bf16_t)nv;
                    }
                }
            }
        }
    }
}

// ---------------------------------------------------------------------------
// 256x256 deep-pipelined TN GEMM (unembed). Round-14 change: all 4 next-tile
// half-stages issue at the top; vmcnt(8) = previous tile's 8 loads done,
// next tile's 8 in flight (full-tile prefetch distance).
// ---------------------------------------------------------------------------
template<int MODE, bool BIAS, bool RELU>
__global__ __launch_bounds__(512, 1)
void gemm256(const bf16_t* __restrict__ A, const bf16_t* __restrict__ Bm,
             char* __restrict__ Out, int ldc,
             const float* __restrict__ bias, int K)
{
    const int mb = blockIdx.x, nb = blockIdx.y;

    __shared__ alignas(16) bf16_t lds[2][2][2][128*64];

    const int tid  = threadIdx.x;
    const int wave = tid >> 6, lane = tid & 63;
    const int wm = wave >> 2, wn = wave & 3;
    const int l16 = lane & 15, lh = lane >> 4;

    const bf16_t* Abase = A  + (long)(mb*256)*K;
    const bf16_t* Bbase = Bm + (long)(nb*256)*K;

    const int c0 = tid,       r0 = c0 >> 3, lc0 = (c0 & 7) ^ (r0 & 7);
    const int c1 = 512 + tid, r1 = c1 >> 3, lc1 = (c1 & 7) ^ (r1 & 7);

    auto stage4 = [&](int buf, int k0) {     // A0,A1,B0,B1: 8 loads/thread
#pragma unroll
        for (int mat=0; mat<2; ++mat)
#pragma unroll
            for (int half=0; half<2; ++half) {
                const bf16_t* src = (mat ? Bbase : Abase) + (long)(half*128)*K + k0;
                bf16_t* dst = &lds[buf][mat][half][0];
                gload16(&src[(long)r0*K + lc0*8], dst + c0*8);
                gload16(&src[(long)r1*K + lc1*8], dst + c1*8);
            }
    };

    f32x4 acc[8][4];
#pragma unroll
    for (int i=0;i<8;i++)
#pragma unroll
        for (int j=0;j<4;j++) { f32x4 zv={0.f,0.f,0.f,0.f}; acc[i][j]=zv; }

    const int NT = K >> 6;
    stage4(0, 0);

    int cur = 0;
    for (int kt = 0; kt < NT; ++kt) {
        const int nxt = cur ^ 1;
        const bool more = (kt+1 < NT);

        if (more) {
            stage4(nxt, (kt+1) << 6);
            asm volatile("s_waitcnt vmcnt(8)" ::: "memory");
        } else {
            asm volatile("s_waitcnt vmcnt(0)" ::: "memory");
        }
        asm volatile("s_barrier" ::: "memory");

        bf16x8 af[4][2], bfr[4][2];
#pragma unroll
        for (int i=0;i<4;i++) {
            int ra = i*16 + l16;
#pragma unroll
            for (int kk=0;kk<2;kk++)
                af[i][kk] = *(const bf16x8*)&lds[cur][0][wm][ra*64 + (((kk*4+lh)^(ra&7))*8)];
        }
#pragma unroll
        for (int j=0;j<2;j++) {
            int rb = (wn&1)*64 + j*16 + l16;
#pragma unroll
            for (int kk=0;kk<2;kk++)
                bfr[j][kk] = *(const bf16x8*)&lds[cur][1][wn>>1][rb*64 + (((kk*4+lh)^(rb&7))*8)];
        }
        __builtin_amdgcn_s_setprio(1);
#pragma unroll
        for (int kk=0;kk<2;kk++)
#pragma unroll
            for (int i=0;i<4;i++)
#pragma unroll
                for (int j=0;j<2;j++)
                    acc[i][j] = __builtin_amdgcn_mfma_f32_16x16x32_bf16(af[i][kk], bfr[j][kk], acc[i][j], 0,0,0);
        __builtin_amdgcn_s_setprio(0);

#pragma unroll
        for (int j=2;j<4;j++) {
            int rb = (wn&1)*64 + j*16 + l16;
#pragma unroll
            for (int kk=0;kk<2;kk++)
                bfr[j][kk] = *(const bf16x8*)&lds[cur][1][wn>>1][rb*64 + (((kk*4+lh)^(rb&7))*8)];
        }
        __builtin_amdgcn_s_setprio(1);
#pragma unroll
        for (int kk=0;kk<2;kk++)
#pragma unroll
            for (int i=0;i<4;i++)
#pragma unroll
                for (int j=2;j<4;j++)
                    acc[i][j] = __builtin_amdgcn_mfma_f32_16x16x32_bf16(af[i][kk], bfr[j][kk], acc[i][j], 0,0,0);
        __builtin_amdgcn_s_setprio(0);

#pragma unroll
        for (int i=0;i<4;i++) {
            int ra = (i+4)*16 + l16;
#pragma unroll
            for (int kk=0;kk<2;kk++)
                af[i][kk] = *(const bf16x8*)&lds[cur][0][wm][ra*64 + (((kk*4+lh)^(ra&7))*8)];
        }
        __builtin_amdgcn_s_setprio(1);
#pragma unroll
        for (int kk=0;kk<2;kk++)
#pragma unroll
            for (int i=0;i<4;i++)
#pragma unroll
                for (int j=0;j<2;j++)
                    acc[i+4][j] = __builtin_amdgcn_mfma_f32_16x16x32_bf16(af[i][kk], bfr[j][kk], acc[i+4][j], 0,0,0);
        __builtin_amdgcn_s_setprio(0);

        __builtin_amdgcn_s_setprio(1);
#pragma unroll
        for (int kk=0;kk<2;kk++)
#pragma unroll
            for (int i=0;i<4;i++)
#pragma unroll
                for (int j=2;j<4;j++)
                    acc[i+4][j] = __builtin_amdgcn_mfma_f32_16x16x32_bf16(af[i][kk], bfr[j][kk], acc[i+4][j], 0,0,0);
        __builtin_amdgcn_s_setprio(0);

        asm volatile("s_barrier" ::: "memory");
        cur = nxt;
    }

    if constexpr (MODE == 1) {
        float* lsl = reinterpret_cast<float*>(&lds[0][0][0][0]) + wave*(32*68);
        const int lrow = lane >> 4;
        const int lcq  = lane & 15;
#pragma unroll
        for (int ch=0; ch<4; ++ch) {
#pragma unroll
            for (int il=0; il<2; ++il)
#pragma unroll
                for (int j=0;j<4;j++)
#pragma unroll
                    for (int r=0;r<4;r++)
                        lsl[(il*16 + lh*4 + r)*68 + j*16 + l16] = acc[ch*2+il][j][r];
#pragma unroll
            for (int u=0; u<8; ++u) {
                int rl = u*4 + lrow;
                f32x4 v = *(const f32x4*)&lsl[rl*68 + lcq*4];
                long row = mb*256 + wm*128 + ch*32 + rl;
                long col = nb*256 + wn*64 + lcq*4;
                __builtin_nontemporal_store(v, (f32x4*)&((float*)Out)[row*ldc + col]);
            }
        }
    } else {
#pragma unroll
        for (int i=0;i<8;i++) {
            int row0 = mb*256 + wm*128 + i*16 + lh*4;
#pragma unroll
            for (int j=0;j<4;j++) {
                int col = nb*256 + wn*64 + j*16 + l16;
                float bv = BIAS ? bias[col] : 0.0f;
#pragma unroll
                for (int r=0;r<4;r++) {
                    int row = row0 + r;
                    float v = acc[i][j][r] + bv;
                    if (RELU) v = v > 0.f ? v : 0.f;
                    ((bf16_t*)Out)[(long)row*ldc + col] = (bf16_t)v;
                }
            }
        }
    }
}

// ---------------------------------------------------------------------------
// Flash attention (causal), KV double-buffered with counted vmcnt.
// ---------------------------------------------------------------------------
__global__ __launch_bounds__(256)
void flash_attn(const bf16_t* __restrict__ qkvf,  // [B][S][3072]
                const bf16_t* __restrict__ vtg,   // [BH][DH][S]
                bf16_t* __restrict__ zf)          // [B][S][DM]
{
    const int qt = blockIdx.x;
    const int bh = blockIdx.y;
    const int b  = bh >> 4, hd = bh & 15;

    __shared__ alignas(16) bf16_t Kl[2][64*64];
    __shared__ alignas(16) bf16_t Vtl[2][64*64];
    __shared__ alignas(16) bf16_t Pl[4*32*64];

    const int tid = threadIdx.x;
    const int wave = tid >> 6, lane = tid & 63;
    const int l16 = lane & 15, lh = lane >> 4;
    const int wq_lo = qt*128 + wave*32;
    bf16_t* Pw = Pl + wave*32*64;

    auto stageKV = [&](int buf, int kv0) {
#pragma unroll
        for (int u=0; u<2; ++u) {
            int c = u*256 + tid;
            int row = c >> 3, lc = (c & 7) ^ (row & 7);
            gload16(&qkvf[((long)b*S + kv0 + row)*3072 + 1024 + hd*64 + lc*8], &Kl[buf][c*8]);
        }
#pragma unroll
        for (int u=0; u<2; ++u) {
            int c = u*256 + tid;
            int row = c >> 3, lc = (c & 7) ^ (row & 7);
            gload16(&vtg[((long)bh*DH + row)*S + kv0 + lc*8], &Vtl[buf][c*8]);
        }
    };

    bf16x8 qr[2][2];
#pragma unroll
    for (int qf=0; qf<2; qf++) {
        int qg = wq_lo + qf*16 + l16;
#pragma unroll
        for (int dhh=0; dhh<2; dhh++)
            qr[qf][dhh] = *(const bf16x8*)&qkvf[((long)b*S + qg)*3072 + hd*64 + dhh*32 + lh*8];
    }

    f32x4 o[4][2];
#pragma unroll
    for (int d=0; d<4; d++)
#pragma unroll
        for (int qf=0; qf<2; qf++) { f32x4 zv={0.f,0.f,0.f,0.f}; o[d][qf]=zv; }
    float mrun[2] = {-1e30f, -1e30f};
    float lrun[2] = {0.f, 0.f};

    const int nt = 2*(qt+1);
    const float C = 0.125f;

    stageKV(0, 0);
    int cur = 0;
    for (int t = 0; t < nt; ++t) {
        const int nxt = cur ^ 1;
        const bool more = (t+1 < nt);
        if (more) {
            stageKV(nxt, (t+1)*64);
            asm volatile("s_waitcnt vmcnt(4)" ::: "memory");
        } else {
            asm volatile("s_waitcnt vmcnt(0)" ::: "memory");
        }
        asm volatile("s_barrier" ::: "memory");

        const int kv0 = t*64;
        f32x4 s[4][2];
#pragma unroll
        for (int f=0; f<4; f++)
#pragma unroll
            for (int qf=0; qf<2; qf++) { f32x4 zv={0.f,0.f,0.f,0.f}; s[f][qf]=zv; }
        __builtin_amdgcn_s_setprio(1);
#pragma unroll
        for (int f=0; f<4; f++) {
            int krow = f*16 + l16;
#pragma unroll
            for (int dhh=0; dhh<2; dhh++) {
                bf16x8 kfr = *(const bf16x8*)&Kl[cur][krow*64 + (((dhh*4+lh) ^ (krow&7))*8)];
#pragma unroll
                for (int qf=0; qf<2; qf++)
                    s[f][qf] = __builtin_amdgcn_mfma_f32_16x16x32_bf16(kfr, qr[qf][dhh], s[f][qf], 0,0,0);
            }
        }
        __builtin_amdgcn_s_setprio(0);

        const bool needmask = (kv0 + 64 > wq_lo);

#pragma unroll
        for (int qf=0; qf<2; qf++) {
            int qg = wq_lo + qf*16 + l16;
            float pmax = -1e30f;
#pragma unroll
            for (int f=0; f<4; f++)
#pragma unroll
                for (int r=0; r<4; r++) {
                    float sv = s[f][qf][r];
                    if (needmask && (kv0 + f*16 + lh*4 + r > qg)) { sv = -1e30f; s[f][qf][r] = sv; }
                    pmax = fmaxf(pmax, sv);
                }
            pmax = fmaxf(pmax, __shfl_xor(pmax, 16));
            pmax = fmaxf(pmax, __shfl_xor(pmax, 32));
            float mnew = fmaxf(mrun[qf], pmax);
            float corr = __expf((mrun[qf] - mnew)*C);
            mrun[qf] = mnew;
            lrun[qf] *= corr;
#pragma unroll
            for (int d=0; d<4; d++) o[d][qf] *= corr;
            float lsum = 0.f;
            int qloc = qf*16 + l16;
#pragma unroll
            for (int f=0; f<4; f++) {
                ushort4 pk;
                float p0 = __expf((s[f][qf][0]-mnew)*C);
                float p1 = __expf((s[f][qf][1]-mnew)*C);
                float p2 = __expf((s[f][qf][2]-mnew)*C);
                float p3 = __expf((s[f][qf][3]-mnew)*C);
                lsum += (p0+p1) + (p2+p3);
                pk.x = bfbits(p0); pk.y = bfbits(p1); pk.z = bfbits(p2); pk.w = bfbits(p3);
                int phys = (f*2 + (lh>>1)) ^ (qloc & 7);
                *(ushort4*)&Pw[qloc*64 + phys*8 + (lh&1)*4] = pk;
            }
            lrun[qf] += lsum;
        }

#pragma unroll
        for (int kh=0; kh<2; kh++) {
            bf16x8 pb[2];
#pragma unroll
            for (int qf=0; qf<2; qf++) {
                int qloc = qf*16 + l16;
                pb[qf] = *(const bf16x8*)&Pw[qloc*64 + (((kh*4+lh) ^ (qloc&7))*8)];
            }
            __builtin_amdgcn_s_setprio(1);
#pragma unroll
            for (int d=0; d<4; d++) {
                int vrow = d*16 + l16;
                bf16x8 va = *(const bf16x8*)&Vtl[cur][vrow*64 + (((kh*4+lh) ^ (vrow&7))*8)];
#pragma unroll
                for (int qf=0; qf<2; qf++)
                    o[d][qf] = __builtin_amdgcn_mfma_f32_16x16x32_bf16(va, pb[qf], o[d][qf], 0,0,0);
            }
            __builtin_amdgcn_s_setprio(0);
        }
        asm volatile("s_barrier" ::: "memory");
        cur = nxt;
    }

#pragma unroll
    for (int qf=0; qf<2; qf++) {
        float lt = lrun[qf];
        lt += __shfl_xor(lt, 16);
        lt += __shfl_xor(lt, 32);
        float inv = 1.0f / lt;
        int qg = wq_lo + qf*16 + l16;
#pragma unroll
        for (int d=0; d<4; d++) {
            ushort4 ov;
            ov.x = bfbits(o[d][qf][0]*inv);
            ov.y = bfbits(o[d][qf][1]*inv);
            ov.z = bfbits(o[d][qf][2]*inv);
            ov.w = bfbits(o[d][qf][3]*inv);
            *(ushort4*)&zf[((long)b*S + qg)*DM + hd*64 + d*16 + lh*4] = ov;
        }
    }
}

// ---------------------------------------------------------------------------
// Weight conversion kernels (vectorized)
// ---------------------------------------------------------------------------
__global__ __launch_bounds__(256) void k_conv_qkv(
    const float* __restrict__ Wq, const float* __restrict__ Wk,
    const float* __restrict__ Wv, bf16_t* __restrict__ out)
{
    long idx = ((long)blockIdx.x*256 + threadIdx.x)*4;
    long l = idx / (3072L*DM);
    long r = idx % (3072L*DM);
    int row = (int)(r / DM), d = (int)(r % DM);
    int sel = row >> 10, rr = row & 1023;
    const float* src = sel==0 ? Wq : (sel==1 ? Wk : Wv);
    float4 v = *(const float4*)&src[(l*1024 + rr)*(long)DM + d];
    ushort4 o;
    o.x = bfbits(v.x); o.y = bfbits(v.y); o.z = bfbits(v.z); o.w = bfbits(v.w);
    *(ushort4*)&out[idx] = o;
}

__global__ __launch_bounds__(256) void k_conv(const float* __restrict__ src,
                                              bf16_t* __restrict__ dst, long n)
{
    long i = ((long)blockIdx.x*256 + threadIdx.x)*4;
    if (i >= n) return;
    float4 v = *(const float4*)&src[i];
    ushort4 o;
    o.x = bfbits(v.x); o.y = bfbits(v.y); o.z = bfbits(v.z); o.w = bfbits(v.w);
    *(ushort4*)&dst[i] = o;
}

// W [DM][NC] f32 -> out [NC][DM] bf16 (tiled transpose; W_U and W_E)
__global__ __launch_bounds__(256) void k_trans(const float* __restrict__ W,
                                               bf16_t* __restrict__ out, int NC)
{
    __shared__ float tile[32][33];
    int n0 = blockIdx.x*32, k0 = blockIdx.y*32;
    int tx = threadIdx.x & 31, ty = threadIdx.x >> 5;
#pragma unroll
    for (int u=0;u<4;u++)
        tile[ty+u*8][tx] = W[(long)(k0+ty+u*8)*NC + n0+tx];
    __syncthreads();
#pragma unroll
    for (int u=0;u<4;u++)
        out[(long)(n0+ty+u*8)*DM + k0+tx] = (bf16_t)tile[tx][ty+u*8];
}

// ---------------------------------------------------------------------------
// Embedding from TRANSPOSED W_E
// ---------------------------------------------------------------------------
__global__ __launch_bounds__(256) void k_embed(const int* __restrict__ tok,
    const bf16_t* __restrict__ WEt, const float* __restrict__ Wpos,
    float* __restrict__ xf, bf16_t* __restrict__ xb)
{
    int bp = blockIdx.x;
    int p  = bp & (S-1);
    int t  = tok[bp];
    int d  = threadIdx.x*4;
    ushort4 e = *(const ushort4*)&WEt[(long)t*DM + d];
    float4  w = *(const float4*)&Wpos[(long)p*DM + d];
    float4 v;
    v.x = b2f(e.x)+w.x; v.y = b2f(e.y)+w.y; v.z = b2f(e.z)+w.z; v.w = b2f(e.w)+w.w;
    *(float4*)&xf[(long)bp*DM + d] = v;
    ushort4 o;
    o.x = bfbits(v.x); o.y = bfbits(v.y); o.z = bfbits(v.z); o.w = bfbits(v.w);
    *(ushort4*)&xb[(long)bp*DM + d] = o;
}

// qkv_flat V-part -> vT[b,h,dh,p], LDS-tiled transpose
__global__ __launch_bounds__(256) void k_permv(const bf16_t* __restrict__ qkv,
    bf16_t* __restrict__ vt)
{
    __shared__ bf16_t tile[64][66];
    const int p0 = blockIdx.x*64;
    const int bh = blockIdx.y;
    const int b  = bh >> 4, hd = bh & 15;
    const int tx = threadIdx.x & 63, ty = threadIdx.x >> 6;
#pragma unroll
    for (int u=0;u<16;u++) {
        int r = u*4 + ty;
        tile[r][tx] = qkv[((long)b*S + p0 + r)*3072 + 2048 + hd*64 + tx];
    }
    __syncthreads();
#pragma unroll
    for (int u=0;u<16;u++) {
        int hh = u*4 + ty;
        vt[(((long)bh)*DH + hh)*S + p0 + tx] = tile[tx][hh];
    }
}

// ---------------------------------------------------------------------------
extern "C" void kernel_launch(void* const* d_in, const int* in_sizes, int n_in,
                              void* d_out, int out_size, void* d_ws, size_t ws_size,
                              hipStream_t stream)
{
    const int*   tokens = (const int*)d_in[0];
    const float* W_E    = (const float*)d_in[1];
    const float* W_pos  = (const float*)d_in[2];
    const float* W_K    = (const float*)d_in[3];
    const float* W_Q    = (const float*)d_in[4];
    const float* W_V    = (const float*)d_in[5];
    const float* W_O    = (const float*)d_in[6];
    const float* W_in   = (const float*)d_in[7];
    const float* b_in   = (const float*)d_in[8];
    const float* W_out  = (const float*)d_in[9];
    const float* b_out  = (const float*)d_in[10];
    const float* W_U    = (const float*)d_in[11];
    float* out = (float*)d_out;

    char* ws = (char*)d_ws;
    long off = 0;
    auto alloc = [&](long bytes)->char* {
        char* p = ws + off; off += (bytes + 255) & ~255L; return p;
    };
    bf16_t* wqkv = (bf16_t*)alloc((long)NL*3072*DM*2);
    bf16_t* wo   = (bf16_t*)alloc((long)NL*DM*DM*2);
    bf16_t* win  = (bf16_t*)alloc((long)NL*DMLP*DM*2);
    bf16_t* wout = (bf16_t*)alloc((long)NL*DM*DMLP*2);
    bf16_t* wut  = (bf16_t*)alloc((long)DV*DM*2);
    bf16_t* wet  = (bf16_t*)alloc((long)DV*DM*2);
    float*  xf   = (float*)alloc((long)MTOK*DM*4);
    bf16_t* xb   = (bf16_t*)alloc((long)MTOK*DM*2);
    bf16_t* qkvf = (bf16_t*)alloc((long)MTOK*3072*2);
    bf16_t* vt   = (bf16_t*)alloc((long)BATCH*NH*S*DH*2);
    bf16_t* zf   = (bf16_t*)alloc((long)MTOK*DM*2);
    bf16_t* post = (bf16_t*)alloc((long)MTOK*DMLP*2);

    // --- weight conversion (per launch; deterministic) ---
    k_conv_qkv<<<(int)(((long)NL*3072*DM)/1024), 256, 0, stream>>>(W_Q, W_K, W_V, wqkv);
    k_conv<<<(int)(((long)NL*DM*DM)/1024),   256, 0, stream>>>(W_O,   wo,   (long)NL*DM*DM);
    k_conv<<<(int)(((long)NL*DMLP*DM)/1024), 256, 0, stream>>>(W_in,  win,  (long)NL*DMLP*DM);
    k_conv<<<(int)(((long)NL*DM*DMLP)/1024), 256, 0, stream>>>(W_out, wout, (long)NL*DM*DMLP);
    k_trans<<<dim3(DV/32, DM/32), 256, 0, stream>>>(W_U, wut, DV);
    k_trans<<<dim3(DV/32, DM/32), 256, 0, stream>>>(W_E, wet, DV);

    // --- embed ---
    k_embed<<<MTOK, 256, 0, stream>>>(tokens, wet, W_pos, xf, xb);

    for (int l = 0; l < NL; ++l) {
        // QKV (fused N=3072)
        gemm128d<0,false,false><<<dim3(MTOK/128, 3072/128), 256, 0, stream>>>(
            xb, wqkv + (long)l*3072*DM, (char*)qkvf, 3072, nullptr, nullptr, nullptr, DM);
        k_permv<<<dim3(S/64, BATCH*NH), 256, 0, stream>>>(qkvf, vt);

        // fused causal attention -> z_flat (KV double-buffered)
        flash_attn<<<dim3(S/128, BATCH*NH), 256, 0, stream>>>(qkvf, vt, zf);

        // attn_out = z_flat @ W_O^T, fused residual add into x
        gemm128d<2,false,false><<<dim3(MTOK/128, DM/128), 256, 0, stream>>>(
            zf, wo + (long)l*DM*DM, nullptr, DM, nullptr, xf, xb, DM);
        // MLP in: relu(x @ W_in^T + b_in)
        gemm128d<0,true,true><<<dim3(MTOK/128, DMLP/128), 256, 0, stream>>>(
            xb, win + (long)l*DMLP*DM, (char*)post, DMLP,
            b_in + (long)l*DMLP, nullptr, nullptr, DM);
        // MLP out + b_out, fused residual add into x
        gemm128d<2,true,false><<<dim3(MTOK/128, DM/128), 256, 0, stream>>>(
            post, wout + (long)l*DM*DMLP, nullptr, DM,
            b_out + (long)l*DM, xf, xb, DMLP);
    }

    // logits = x @ W_U (f32 out, full-line nt stores): 256-tile
    gemm256<1,false,false><<<dim3(MTOK/256, DV/256), 512, 0, stream>>>(
        xb, wut, (char*)out, DV, nullptr, DM);
}

// Round 15
// 1424.622 us; speedup vs baseline: 1.1911x; 1.0178x over previous
//
#include <hip/hip_runtime.h>
#include <hip/hip_bf16.h>
#include <math.h>

// Model dims
#define DV   32000
#define DM   1024
#define DMLP 4096
#define DH   64
#define NH   16
#define NL   4
#define BATCH 2
#define S    2048
#define MTOK (BATCH*S)   // 4096 tokens

typedef __bf16 bf16_t;
typedef bf16_t bf16x8 __attribute__((ext_vector_type(8)));
typedef float  f32x4  __attribute__((ext_vector_type(4)));

#define AS1 __attribute__((address_space(1)))
#define AS3 __attribute__((address_space(3)))

__device__ __forceinline__ void gload16(const bf16_t* g, bf16_t* l) {
    __builtin_amdgcn_global_load_lds((const AS1 void*)g, (AS3 void*)l, 16, 0, 0);
}

__device__ __forceinline__ unsigned short bfbits(float v) {
    union { bf16_t b; unsigned short u; } c; c.b = (bf16_t)v; return c.u;
}
__device__ __forceinline__ float b2f(unsigned short u) {
    union { float f; unsigned v; } c; c.v = ((unsigned)u) << 16; return c.f;
}

// ---------------------------------------------------------------------------
// 128x128 double-buffered TN GEMM, full-tile-ahead prefetch (round-14:
// all next-tile stages issue at the top; vmcnt(8) waits only for the
// PREVIOUS tile's 8 loads -> full-tile prefetch distance; -115us total).
// MODE 0: bf16 out (+bias/relu). MODE 1: f32 out (LDS-transposed nt).
// MODE 2: resid_f32 += acc(+bias); residb=bf16.
// ---------------------------------------------------------------------------
template<int MODE, bool BIAS, bool RELU>
__global__ __launch_bounds__(256, 2)
void gemm128d(const bf16_t* __restrict__ A, const bf16_t* __restrict__ Bm,
              char* __restrict__ Out, int ldc,
              const float* __restrict__ bias,
              float* __restrict__ resid, bf16_t* __restrict__ residb,
              int K)
{
    const int mb = blockIdx.x, nb = blockIdx.y;

    __shared__ alignas(16) bf16_t lds[2][2][128*64];

    const int tid  = threadIdx.x;
    const int wave = tid >> 6, lane = tid & 63;
    const int wm = wave >> 1, wn = wave & 1;
    const int l16 = lane & 15, lh = lane >> 4;

    const bf16_t* Abase = A  + (long)(mb*128)*K;
    const bf16_t* Bbase = Bm + (long)(nb*128)*K;

    auto stage2 = [&](int buf, int k0) {     // A + B tile: 8 loads/thread
#pragma unroll
        for (int mat=0; mat<2; ++mat) {
            const bf16_t* src = (mat ? Bbase : Abase) + k0;
            bf16_t* dst = &lds[buf][mat][0];
#pragma unroll
            for (int u=0; u<4; ++u) {
                int c = u*256 + tid;
                int row = c >> 3, lc = (c & 7) ^ (row & 7);
                gload16(&src[(long)row*K + lc*8], dst + c*8);
            }
        }
    };

    f32x4 acc[4][4];
#pragma unroll
    for (int i=0;i<4;i++)
#pragma unroll
        for (int j=0;j<4;j++) { f32x4 zv={0.f,0.f,0.f,0.f}; acc[i][j]=zv; }

    const int NT = K >> 6;
    stage2(0, 0);

    int cur = 0;
    for (int kt = 0; kt < NT; ++kt) {
        const int nxt = cur ^ 1;
        const bool more = (kt+1 < NT);

        if (more) {
            stage2(nxt, (kt+1) << 6);
            asm volatile("s_waitcnt vmcnt(8)" ::: "memory");
        } else {
            asm volatile("s_waitcnt vmcnt(0)" ::: "memory");
        }
        asm volatile("s_barrier" ::: "memory");

        bf16x8 af[4][2], bfr[4][2];
#pragma unroll
        for (int i=0;i<4;i++) {
            int ra = wm*64 + i*16 + l16;
#pragma unroll
            for (int kk=0;kk<2;kk++)
                af[i][kk] = *(const bf16x8*)&lds[cur][0][ra*64 + (((kk*4+lh)^(ra&7))*8)];
        }
#pragma unroll
        for (int j=0;j<2;j++) {
            int rb = wn*64 + j*16 + l16;
#pragma unroll
            for (int kk=0;kk<2;kk++)
                bfr[j][kk] = *(const bf16x8*)&lds[cur][1][rb*64 + (((kk*4+lh)^(rb&7))*8)];
        }
        __builtin_amdgcn_s_setprio(1);
#pragma unroll
        for (int kk=0;kk<2;kk++)
#pragma unroll
            for (int i=0;i<4;i++)
#pragma unroll
                for (int j=0;j<2;j++)
                    acc[i][j] = __builtin_amdgcn_mfma_f32_16x16x32_bf16(af[i][kk], bfr[j][kk], acc[i][j], 0,0,0);
        __builtin_amdgcn_s_setprio(0);

#pragma unroll
        for (int j=2;j<4;j++) {
            int rb = wn*64 + j*16 + l16;
#pragma unroll
            for (int kk=0;kk<2;kk++)
                bfr[j][kk] = *(const bf16x8*)&lds[cur][1][rb*64 + (((kk*4+lh)^(rb&7))*8)];
        }
        __builtin_amdgcn_s_setprio(1);
#pragma unroll
        for (int kk=0;kk<2;kk++)
#pragma unroll
            for (int i=0;i<4;i++)
#pragma unroll
                for (int j=2;j<4;j++)
                    acc[i][j] = __builtin_amdgcn_mfma_f32_16x16x32_bf16(af[i][kk], bfr[j][kk], acc[i][j], 0,0,0);
        __builtin_amdgcn_s_setprio(0);

        asm volatile("s_barrier" ::: "memory");
        cur = nxt;
    }

    if constexpr (MODE == 1) {
        float* lsl = reinterpret_cast<float*>(&lds[0][0][0]) + wave*(32*68);
        const int lrow = lane >> 4;
        const int lcq  = lane & 15;
#pragma unroll
        for (int ch=0; ch<2; ++ch) {
#pragma unroll
            for (int il=0; il<2; ++il)
#pragma unroll
                for (int j=0;j<4;j++)
#pragma unroll
                    for (int r=0;r<4;r++)
                        lsl[(il*16 + lh*4 + r)*68 + j*16 + l16] = acc[ch*2+il][j][r];
#pragma unroll
            for (int u=0; u<8; ++u) {
                int rl = u*4 + lrow;
                f32x4 v = *(const f32x4*)&lsl[rl*68 + lcq*4];
                long row = mb*128 + wm*64 + ch*32 + rl;
                long col = nb*128 + wn*64 + lcq*4;
                __builtin_nontemporal_store(v, (f32x4*)&((float*)Out)[row*ldc + col]);
            }
        }
    } else {
#pragma unroll
        for (int i=0;i<4;i++) {
            int row0 = mb*128 + wm*64 + i*16 + lh*4;
#pragma unroll
            for (int j=0;j<4;j++) {
                int col = nb*128 + wn*64 + j*16 + l16;
                float bv = BIAS ? bias[col] : 0.0f;
#pragma unroll
                for (int r=0;r<4;r++) {
                    int row = row0 + r;
                    float v = acc[i][j][r] + bv;
                    if (RELU) v = v > 0.f ? v : 0.f;
                    if constexpr (MODE == 0) {
                        ((bf16_t*)Out)[(long)row*ldc + col] = (bf16_t)v;
                    } else {
                        long o2 = (long)row*ldc + col;
                        float nv = resid[o2] + v;
                        resid[o2]  = nv;
                        residb[o2] = (bf16_t)nv;
                    }
                }
            }
        }
    }
}

// ---------------------------------------------------------------------------
// 256x256 deep-pipelined TN GEMM (unembed), full-tile-ahead prefetch.
// ---------------------------------------------------------------------------
template<int MODE, bool BIAS, bool RELU>
__global__ __launch_bounds__(512, 1)
void gemm256(const bf16_t* __restrict__ A, const bf16_t* __restrict__ Bm,
             char* __restrict__ Out, int ldc,
             const float* __restrict__ bias, int K)
{
    const int mb = blockIdx.x, nb = blockIdx.y;

    __shared__ alignas(16) bf16_t lds[2][2][2][128*64];

    const int tid  = threadIdx.x;
    const int wave = tid >> 6, lane = tid & 63;
    const int wm = wave >> 2, wn = wave & 3;
    const int l16 = lane & 15, lh = lane >> 4;

    const bf16_t* Abase = A  + (long)(mb*256)*K;
    const bf16_t* Bbase = Bm + (long)(nb*256)*K;

    const int c0 = tid,       r0 = c0 >> 3, lc0 = (c0 & 7) ^ (r0 & 7);
    const int c1 = 512 + tid, r1 = c1 >> 3, lc1 = (c1 & 7) ^ (r1 & 7);

    auto stage4 = [&](int buf, int k0) {
#pragma unroll
        for (int mat=0; mat<2; ++mat)
#pragma unroll
            for (int half=0; half<2; ++half) {
                const bf16_t* src = (mat ? Bbase : Abase) + (long)(half*128)*K + k0;
                bf16_t* dst = &lds[buf][mat][half][0];
                gload16(&src[(long)r0*K + lc0*8], dst + c0*8);
                gload16(&src[(long)r1*K + lc1*8], dst + c1*8);
            }
    };

    f32x4 acc[8][4];
#pragma unroll
    for (int i=0;i<8;i++)
#pragma unroll
        for (int j=0;j<4;j++) { f32x4 zv={0.f,0.f,0.f,0.f}; acc[i][j]=zv; }

    const int NT = K >> 6;
    stage4(0, 0);

    int cur = 0;
    for (int kt = 0; kt < NT; ++kt) {
        const int nxt = cur ^ 1;
        const bool more = (kt+1 < NT);

        if (more) {
            stage4(nxt, (kt+1) << 6);
            asm volatile("s_waitcnt vmcnt(8)" ::: "memory");
        } else {
            asm volatile("s_waitcnt vmcnt(0)" ::: "memory");
        }
        asm volatile("s_barrier" ::: "memory");

        bf16x8 af[4][2], bfr[4][2];
#pragma unroll
        for (int i=0;i<4;i++) {
            int ra = i*16 + l16;
#pragma unroll
            for (int kk=0;kk<2;kk++)
                af[i][kk] = *(const bf16x8*)&lds[cur][0][wm][ra*64 + (((kk*4+lh)^(ra&7))*8)];
        }
#pragma unroll
        for (int j=0;j<2;j++) {
            int rb = (wn&1)*64 + j*16 + l16;
#pragma unroll
            for (int kk=0;kk<2;kk++)
                bfr[j][kk] = *(const bf16x8*)&lds[cur][1][wn>>1][rb*64 + (((kk*4+lh)^(rb&7))*8)];
        }
        __builtin_amdgcn_s_setprio(1);
#pragma unroll
        for (int kk=0;kk<2;kk++)
#pragma unroll
            for (int i=0;i<4;i++)
#pragma unroll
                for (int j=0;j<2;j++)
                    acc[i][j] = __builtin_amdgcn_mfma_f32_16x16x32_bf16(af[i][kk], bfr[j][kk], acc[i][j], 0,0,0);
        __builtin_amdgcn_s_setprio(0);

#pragma unroll
        for (int j=2;j<4;j++) {
            int rb = (wn&1)*64 + j*16 + l16;
#pragma unroll
            for (int kk=0;kk<2;kk++)
                bfr[j][kk] = *(const bf16x8*)&lds[cur][1][wn>>1][rb*64 + (((kk*4+lh)^(rb&7))*8)];
        }
        __builtin_amdgcn_s_setprio(1);
#pragma unroll
        for (int kk=0;kk<2;kk++)
#pragma unroll
            for (int i=0;i<4;i++)
#pragma unroll
                for (int j=2;j<4;j++)
                    acc[i][j] = __builtin_amdgcn_mfma_f32_16x16x32_bf16(af[i][kk], bfr[j][kk], acc[i][j], 0,0,0);
        __builtin_amdgcn_s_setprio(0);

#pragma unroll
        for (int i=0;i<4;i++) {
            int ra = (i+4)*16 + l16;
#pragma unroll
            for (int kk=0;kk<2;kk++)
                af[i][kk] = *(const bf16x8*)&lds[cur][0][wm][ra*64 + (((kk*4+lh)^(ra&7))*8)];
        }
        __builtin_amdgcn_s_setprio(1);
#pragma unroll
        for (int kk=0;kk<2;kk++)
#pragma unroll
            for (int i=0;i<4;i++)
#pragma unroll
                for (int j=0;j<2;j++)
                    acc[i+4][j] = __builtin_amdgcn_mfma_f32_16x16x32_bf16(af[i][kk], bfr[j][kk], acc[i+4][j], 0,0,0);
        __builtin_amdgcn_s_setprio(0);

        __builtin_amdgcn_s_setprio(1);
#pragma unroll
        for (int kk=0;kk<2;kk++)
#pragma unroll
            for (int i=0;i<4;i++)
#pragma unroll
                for (int j=2;j<4;j++)
                    acc[i+4][j] = __builtin_amdgcn_mfma_f32_16x16x32_bf16(af[i][kk], bfr[j][kk], acc[i+4][j], 0,0,0);
        __builtin_amdgcn_s_setprio(0);

        asm volatile("s_barrier" ::: "memory");
        cur = nxt;
    }

    if constexpr (MODE == 1) {
        float* lsl = reinterpret_cast<float*>(&lds[0][0][0][0]) + wave*(32*68);
        const int lrow = lane >> 4;
        const int lcq  = lane & 15;
#pragma unroll
        for (int ch=0; ch<4; ++ch) {
#pragma unroll
            for (int il=0; il<2; ++il)
#pragma unroll
                for (int j=0;j<4;j++)
#pragma unroll
                    for (int r=0;r<4;r++)
                        lsl[(il*16 + lh*4 + r)*68 + j*16 + l16] = acc[ch*2+il][j][r];
#pragma unroll
            for (int u=0; u<8; ++u) {
                int rl = u*4 + lrow;
                f32x4 v = *(const f32x4*)&lsl[rl*68 + lcq*4];
                long row = mb*256 + wm*128 + ch*32 + rl;
                long col = nb*256 + wn*64 + lcq*4;
                __builtin_nontemporal_store(v, (f32x4*)&((float*)Out)[row*ldc + col]);
            }
        }
    } else {
#pragma unroll
        for (int i=0;i<8;i++) {
            int row0 = mb*256 + wm*128 + i*16 + lh*4;
#pragma unroll
            for (int j=0;j<4;j++) {
                int col = nb*256 + wn*64 + j*16 + l16;
                float bv = BIAS ? bias[col] : 0.0f;
#pragma unroll
                for (int r=0;r<4;r++) {
                    int row = row0 + r;
                    float v = acc[i][j][r] + bv;
                    if (RELU) v = v > 0.f ? v : 0.f;
                    ((bf16_t*)Out)[(long)row*ldc + col] = (bf16_t)v;
                }
            }
        }
    }
}

// ---------------------------------------------------------------------------
// Flash attention (causal), KV double-buffered, LOAD-BALANCED:
// grid (S/256, BATCH*NH); block x handles q-tiles x and 15-x sequentially
// -> uniform 34 KV-tile-units per block (was 2..32 across blocks; CU-mates
// shared the same qt, so the qt=15 CUs were a ~2-4x long pole).
// ---------------------------------------------------------------------------
__global__ __launch_bounds__(256)
void flash_attn(const bf16_t* __restrict__ qkvf,  // [B][S][3072]
                const bf16_t* __restrict__ vtg,   // [BH][DH][S]
                bf16_t* __restrict__ zf)          // [B][S][DM]
{
    const int bh = blockIdx.y;
    const int b  = bh >> 4, hd = bh & 15;

    __shared__ alignas(16) bf16_t Kl[2][64*64];
    __shared__ alignas(16) bf16_t Vtl[2][64*64];
    __shared__ alignas(16) bf16_t Pl[4*32*64];

    const int tid = threadIdx.x;
    const int wave = tid >> 6, lane = tid & 63;
    const int l16 = lane & 15, lh = lane >> 4;
    bf16_t* Pw = Pl + wave*32*64;

    auto stageKV = [&](int buf, int kv0) {
#pragma unroll
        for (int u=0; u<2; ++u) {
            int c = u*256 + tid;
            int row = c >> 3, lc = (c & 7) ^ (row & 7);
            gload16(&qkvf[((long)b*S + kv0 + row)*3072 + 1024 + hd*64 + lc*8], &Kl[buf][c*8]);
        }
#pragma unroll
        for (int u=0; u<2; ++u) {
            int c = u*256 + tid;
            int row = c >> 3, lc = (c & 7) ^ (row & 7);
            gload16(&vtg[((long)bh*DH + row)*S + kv0 + lc*8], &Vtl[buf][c*8]);
        }
    };

    const float C = 0.125f;

#pragma unroll 1
    for (int pass = 0; pass < 2; ++pass) {
        const int qt = pass == 0 ? (int)blockIdx.x : 15 - (int)blockIdx.x;
        const int wq_lo = qt*128 + wave*32;

        bf16x8 qr[2][2];
#pragma unroll
        for (int qf=0; qf<2; qf++) {
            int qg = wq_lo + qf*16 + l16;
#pragma unroll
            for (int dhh=0; dhh<2; dhh++)
                qr[qf][dhh] = *(const bf16x8*)&qkvf[((long)b*S + qg)*3072 + hd*64 + dhh*32 + lh*8];
        }

        f32x4 o[4][2];
#pragma unroll
        for (int d=0; d<4; d++)
#pragma unroll
            for (int qf=0; qf<2; qf++) { f32x4 zv={0.f,0.f,0.f,0.f}; o[d][qf]=zv; }
        float mrun[2] = {-1e30f, -1e30f};
        float lrun[2] = {0.f, 0.f};

        const int nt = 2*(qt+1);

        __syncthreads();          // LDS safe to (re)stage
        stageKV(0, 0);
        int cur = 0;
        for (int t = 0; t < nt; ++t) {
            const int nxt = cur ^ 1;
            const bool more = (t+1 < nt);
            if (more) {
                stageKV(nxt, (t+1)*64);
                asm volatile("s_waitcnt vmcnt(4)" ::: "memory");
            } else {
                asm volatile("s_waitcnt vmcnt(0)" ::: "memory");
            }
            asm volatile("s_barrier" ::: "memory");

            const int kv0 = t*64;
            f32x4 s[4][2];
#pragma unroll
            for (int f=0; f<4; f++)
#pragma unroll
                for (int qf=0; qf<2; qf++) { f32x4 zv={0.f,0.f,0.f,0.f}; s[f][qf]=zv; }
            __builtin_amdgcn_s_setprio(1);
#pragma unroll
            for (int f=0; f<4; f++) {
                int krow = f*16 + l16;
#pragma unroll
                for (int dhh=0; dhh<2; dhh++) {
                    bf16x8 kfr = *(const bf16x8*)&Kl[cur][krow*64 + (((dhh*4+lh) ^ (krow&7))*8)];
#pragma unroll
                    for (int qf=0; qf<2; qf++)
                        s[f][qf] = __builtin_amdgcn_mfma_f32_16x16x32_bf16(kfr, qr[qf][dhh], s[f][qf], 0,0,0);
                }
            }
            __builtin_amdgcn_s_setprio(0);

            const bool needmask = (kv0 + 64 > wq_lo);

#pragma unroll
            for (int qf=0; qf<2; qf++) {
                int qg = wq_lo + qf*16 + l16;
                float pmax = -1e30f;
#pragma unroll
                for (int f=0; f<4; f++)
#pragma unroll
                    for (int r=0; r<4; r++) {
                        float sv = s[f][qf][r];
                        if (needmask && (kv0 + f*16 + lh*4 + r > qg)) { sv = -1e30f; s[f][qf][r] = sv; }
                        pmax = fmaxf(pmax, sv);
                    }
                pmax = fmaxf(pmax, __shfl_xor(pmax, 16));
                pmax = fmaxf(pmax, __shfl_xor(pmax, 32));
                float mnew = fmaxf(mrun[qf], pmax);
                float corr = __expf((mrun[qf] - mnew)*C);
                mrun[qf] = mnew;
                lrun[qf] *= corr;
#pragma unroll
                for (int d=0; d<4; d++) o[d][qf] *= corr;
                float lsum = 0.f;
                int qloc = qf*16 + l16;
#pragma unroll
                for (int f=0; f<4; f++) {
                    ushort4 pk;
                    float p0 = __expf((s[f][qf][0]-mnew)*C);
                    float p1 = __expf((s[f][qf][1]-mnew)*C);
                    float p2 = __expf((s[f][qf][2]-mnew)*C);
                    float p3 = __expf((s[f][qf][3]-mnew)*C);
                    lsum += (p0+p1) + (p2+p3);
                    pk.x = bfbits(p0); pk.y = bfbits(p1); pk.z = bfbits(p2); pk.w = bfbits(p3);
                    int phys = (f*2 + (lh>>1)) ^ (qloc & 7);
                    *(ushort4*)&Pw[qloc*64 + phys*8 + (lh&1)*4] = pk;
                }
                lrun[qf] += lsum;
            }

#pragma unroll
            for (int kh=0; kh<2; kh++) {
                bf16x8 pb[2];
#pragma unroll
                for (int qf=0; qf<2; qf++) {
                    int qloc = qf*16 + l16;
                    pb[qf] = *(const bf16x8*)&Pw[qloc*64 + (((kh*4+lh) ^ (qloc&7))*8)];
                }
                __builtin_amdgcn_s_setprio(1);
#pragma unroll
                for (int d=0; d<4; d++) {
                    int vrow = d*16 + l16;
                    bf16x8 va = *(const bf16x8*)&Vtl[cur][vrow*64 + (((kh*4+lh) ^ (vrow&7))*8)];
#pragma unroll
                    for (int qf=0; qf<2; qf++)
                        o[d][qf] = __builtin_amdgcn_mfma_f32_16x16x32_bf16(va, pb[qf], o[d][qf], 0,0,0);
                }
                __builtin_amdgcn_s_setprio(0);
            }
            asm volatile("s_barrier" ::: "memory");
            cur = nxt;
        }

#pragma unroll
        for (int qf=0; qf<2; qf++) {
            float lt = lrun[qf];
            lt += __shfl_xor(lt, 16);
            lt += __shfl_xor(lt, 32);
            float inv = 1.0f / lt;
            int qg = wq_lo + qf*16 + l16;
#pragma unroll
            for (int d=0; d<4; d++) {
                ushort4 ov;
                ov.x = bfbits(o[d][qf][0]*inv);
                ov.y = bfbits(o[d][qf][1]*inv);
                ov.z = bfbits(o[d][qf][2]*inv);
                ov.w = bfbits(o[d][qf][3]*inv);
                *(ushort4*)&zf[((long)b*S + qg)*DM + hd*64 + d*16 + lh*4] = ov;
            }
        }
    }
}

// ---------------------------------------------------------------------------
// Weight conversion kernels (vectorized)
// ---------------------------------------------------------------------------
__global__ __launch_bounds__(256) void k_conv_qkv(
    const float* __restrict__ Wq, const float* __restrict__ Wk,
    const float* __restrict__ Wv, bf16_t* __restrict__ out)
{
    long idx = ((long)blockIdx.x*256 + threadIdx.x)*4;
    long l = idx / (3072L*DM);
    long r = idx % (3072L*DM);
    int row = (int)(r / DM), d = (int)(r % DM);
    int sel = row >> 10, rr = row & 1023;
    const float* src = sel==0 ? Wq : (sel==1 ? Wk : Wv);
    float4 v = *(const float4*)&src[(l*1024 + rr)*(long)DM + d];
    ushort4 o;
    o.x = bfbits(v.x); o.y = bfbits(v.y); o.z = bfbits(v.z); o.w = bfbits(v.w);
    *(ushort4*)&out[idx] = o;
}

__global__ __launch_bounds__(256) void k_conv(const float* __restrict__ src,
                                              bf16_t* __restrict__ dst, long n)
{
    long i = ((long)blockIdx.x*256 + threadIdx.x)*4;
    if (i >= n) return;
    float4 v = *(const float4*)&src[i];
    ushort4 o;
    o.x = bfbits(v.x); o.y = bfbits(v.y); o.z = bfbits(v.z); o.w = bfbits(v.w);
    *(ushort4*)&dst[i] = o;
}

// W [DM][NC] f32 -> out [NC][DM] bf16 (tiled transpose; W_U and W_E)
__global__ __launch_bounds__(256) void k_trans(const float* __restrict__ W,
                                               bf16_t* __restrict__ out, int NC)
{
    __shared__ float tile[32][33];
    int n0 = blockIdx.x*32, k0 = blockIdx.y*32;
    int tx = threadIdx.x & 31, ty = threadIdx.x >> 5;
#pragma unroll
    for (int u=0;u<4;u++)
        tile[ty+u*8][tx] = W[(long)(k0+ty+u*8)*NC + n0+tx];
    __syncthreads();
#pragma unroll
    for (int u=0;u<4;u++)
        out[(long)(n0+ty+u*8)*DM + k0+tx] = (bf16_t)tile[tx][ty+u*8];
}

// ---------------------------------------------------------------------------
// Embedding from TRANSPOSED W_E
// ---------------------------------------------------------------------------
__global__ __launch_bounds__(256) void k_embed(const int* __restrict__ tok,
    const bf16_t* __restrict__ WEt, const float* __restrict__ Wpos,
    float* __restrict__ xf, bf16_t* __restrict__ xb)
{
    int bp = blockIdx.x;
    int p  = bp & (S-1);
    int t  = tok[bp];
    int d  = threadIdx.x*4;
    ushort4 e = *(const ushort4*)&WEt[(long)t*DM + d];
    float4  w = *(const float4*)&Wpos[(long)p*DM + d];
    float4 v;
    v.x = b2f(e.x)+w.x; v.y = b2f(e.y)+w.y; v.z = b2f(e.z)+w.z; v.w = b2f(e.w)+w.w;
    *(float4*)&xf[(long)bp*DM + d] = v;
    ushort4 o;
    o.x = bfbits(v.x); o.y = bfbits(v.y); o.z = bfbits(v.z); o.w = bfbits(v.w);
    *(ushort4*)&xb[(long)bp*DM + d] = o;
}

// qkv_flat V-part -> vT[b,h,dh,p], LDS-tiled transpose
__global__ __launch_bounds__(256) void k_permv(const bf16_t* __restrict__ qkv,
    bf16_t* __restrict__ vt)
{
    __shared__ bf16_t tile[64][66];
    const int p0 = blockIdx.x*64;
    const int bh = blockIdx.y;
    const int b  = bh >> 4, hd = bh & 15;
    const int tx = threadIdx.x & 63, ty = threadIdx.x >> 6;
#pragma unroll
    for (int u=0;u<16;u++) {
        int r = u*4 + ty;
        tile[r][tx] = qkv[((long)b*S + p0 + r)*3072 + 2048 + hd*64 + tx];
    }
    __syncthreads();
#pragma unroll
    for (int u=0;u<16;u++) {
        int hh = u*4 + ty;
        vt[(((long)bh)*DH + hh)*S + p0 + tx] = tile[tx][hh];
    }
}

// ---------------------------------------------------------------------------
extern "C" void kernel_launch(void* const* d_in, const int* in_sizes, int n_in,
                              void* d_out, int out_size, void* d_ws, size_t ws_size,
                              hipStream_t stream)
{
    const int*   tokens = (const int*)d_in[0];
    const float* W_E    = (const float*)d_in[1];
    const float* W_pos  = (const float*)d_in[2];
    const float* W_K    = (const float*)d_in[3];
    const float* W_Q    = (const float*)d_in[4];
    const float* W_V    = (const float*)d_in[5];
    const float* W_O    = (const float*)d_in[6];
    const float* W_in   = (const float*)d_in[7];
    const float* b_in   = (const float*)d_in[8];
    const float* W_out  = (const float*)d_in[9];
    const float* b_out  = (const float*)d_in[10];
    const float* W_U    = (const float*)d_in[11];
    float* out = (float*)d_out;

    char* ws = (char*)d_ws;
    long off = 0;
    auto alloc = [&](long bytes)->char* {
        char* p = ws + off; off += (bytes + 255) & ~255L; return p;
    };
    bf16_t* wqkv = (bf16_t*)alloc((long)NL*3072*DM*2);
    bf16_t* wo   = (bf16_t*)alloc((long)NL*DM*DM*2);
    bf16_t* win  = (bf16_t*)alloc((long)NL*DMLP*DM*2);
    bf16_t* wout = (bf16_t*)alloc((long)NL*DM*DMLP*2);
    bf16_t* wut  = (bf16_t*)alloc((long)DV*DM*2);
    bf16_t* wet  = (bf16_t*)alloc((long)DV*DM*2);
    float*  xf   = (float*)alloc((long)MTOK*DM*4);
    bf16_t* xb   = (bf16_t*)alloc((long)MTOK*DM*2);
    bf16_t* qkvf = (bf16_t*)alloc((long)MTOK*3072*2);
    bf16_t* vt   = (bf16_t*)alloc((long)BATCH*NH*S*DH*2);
    bf16_t* zf   = (bf16_t*)alloc((long)MTOK*DM*2);
    bf16_t* post = (bf16_t*)alloc((long)MTOK*DMLP*2);

    // --- weight conversion (per launch; deterministic) ---
    k_conv_qkv<<<(int)(((long)NL*3072*DM)/1024), 256, 0, stream>>>(W_Q, W_K, W_V, wqkv);
    k_conv<<<(int)(((long)NL*DM*DM)/1024),   256, 0, stream>>>(W_O,   wo,   (long)NL*DM*DM);
    k_conv<<<(int)(((long)NL*DMLP*DM)/1024), 256, 0, stream>>>(W_in,  win,  (long)NL*DMLP*DM);
    k_conv<<<(int)(((long)NL*DM*DMLP)/1024), 256, 0, stream>>>(W_out, wout, (long)NL*DM*DMLP);
    k_trans<<<dim3(DV/32, DM/32), 256, 0, stream>>>(W_U, wut, DV);
    k_trans<<<dim3(DV/32, DM/32), 256, 0, stream>>>(W_E, wet, DV);

    // --- embed ---
    k_embed<<<MTOK, 256, 0, stream>>>(tokens, wet, W_pos, xf, xb);

    for (int l = 0; l < NL; ++l) {
        // QKV (fused N=3072)
        gemm128d<0,false,false><<<dim3(MTOK/128, 3072/128), 256, 0, stream>>>(
            xb, wqkv + (long)l*3072*DM, (char*)qkvf, 3072, nullptr, nullptr, nullptr, DM);
        k_permv<<<dim3(S/64, BATCH*NH), 256, 0, stream>>>(qkvf, vt);

        // fused causal attention -> z_flat (load-balanced paired q-tiles)
        flash_attn<<<dim3(S/256, BATCH*NH), 256, 0, stream>>>(qkvf, vt, zf);

        // attn_out = z_flat @ W_O^T, fused residual add into x
        gemm128d<2,false,false><<<dim3(MTOK/128, DM/128), 256, 0, stream>>>(
            zf, wo + (long)l*DM*DM, nullptr, DM, nullptr, xf, xb, DM);
        // MLP in: relu(x @ W_in^T + b_in)
        gemm128d<0,true,true><<<dim3(MTOK/128, DMLP/128), 256, 0, stream>>>(
            xb, win + (long)l*DMLP*DM, (char*)post, DMLP,
            b_in + (long)l*DMLP, nullptr, nullptr, DM);
        // MLP out + b_out, fused residual add into x
        gemm128d<2,true,false><<<dim3(MTOK/128, DM/128), 256, 0, stream>>>(
            post, wout + (long)l*DM*DMLP, nullptr, DM,
            b_out + (long)l*DM, xf, xb, DMLP);
    }

    // logits = x @ W_U (f32 out, full-line nt stores): 256-tile
    gemm256<1,false,false><<<dim3(MTOK/256, DV/256), 512, 0, stream>>>(
        xb, wut, (char*)out, DV, nullptr, DM);
}